// Round 1
// baseline (11959.914 us; speedup 1.0000x reference)
//
#include <hip/hip_runtime.h>
#include <math.h>

#define TT 512
#define BB 256
#define FF 64
#define HH 256
#define AA 8
#define BC 4            // batch rows per workgroup
#define NWG (BB / BC)   // 64 workgroups

// ws layout (floats): W1T [64][256] | W_ihT [256][768] | W_hhT [256][768]
#define W1T_OFF   0
#define WIHT_OFF  (FF * HH)                 // 16384
#define WHHT_OFF  (WIHT_OFF + HH * 3 * HH)  // 16384 + 196608

__global__ __launch_bounds__(256) void transpose_weights(
    const float* __restrict__ W1, const float* __restrict__ W_ih,
    const float* __restrict__ W_hh, float* __restrict__ ws) {
  int idx = blockIdx.x * 256 + threadIdx.x;
  // W1T[k*256 + h] = W1[h*64 + k]
  if (idx < FF * HH) {
    int k = idx >> 8, h = idx & 255;
    ws[W1T_OFF + idx] = W1[h * FF + k];
    return;
  }
  int i2 = idx - FF * HH;
  // W_ihT[k*768 + j] = W_ih[j*256 + k]
  if (i2 < HH * 3 * HH) {
    int k = i2 / 768, j = i2 % 768;
    ws[WIHT_OFF + i2] = W_ih[j * HH + k];
    return;
  }
  int i3 = i2 - HH * 3 * HH;
  if (i3 < HH * 3 * HH) {
    int k = i3 / 768, j = i3 % 768;
    ws[WHHT_OFF + i3] = W_hh[j * HH + k];
  }
}

// One WG owns BC=4 batch rows for the whole T-loop. thread = gate column i in [0,256).
// Each thread accumulates, per row r: r-gate (gi+gh), z-gate (gi+gh), gi_n, gh_n.
__global__ __launch_bounds__(256) void gru_seq(
    const float* __restrict__ x, const int* __restrict__ dones,
    const float* __restrict__ b1,
    const float* __restrict__ b_ih, const float* __restrict__ b_hh,
    const float* __restrict__ Wm, const float* __restrict__ bm,
    const float* __restrict__ Wsw, const float* __restrict__ bs,
    const float* __restrict__ ws, float* __restrict__ out) {
  const float* W1T  = ws + W1T_OFF;
  const float* WihT = ws + WIHT_OFF;
  const float* WhhT = ws + WHHT_OFF;
  const int tid = threadIdx.x;      // column i
  const int b0  = blockIdx.x * BC;

  __shared__ float x_lds[BC][FF];
  __shared__ float sf_lds[BC][HH];
  __shared__ float h_lds[BC][HH];

#pragma unroll
  for (int r = 0; r < BC; ++r) h_lds[r][tid] = 0.f;

  const float bih_r = b_ih[tid],        bhh_r = b_hh[tid];
  const float bih_z = b_ih[HH + tid],   bhh_z = b_hh[HH + tid];
  const float bih_n = b_ih[2*HH + tid], bhh_n = b_hh[2*HH + tid];
  const float b1v = b1[tid];

  for (int t = 0; t < TT; ++t) {
    // stage 1: load x slice; apply done-mask to h (owner-column writes only)
    {
      int r = tid >> 6, k = tid & 63;
      x_lds[r][k] = x[((size_t)t * BB + b0 + r) * FF + k];
    }
#pragma unroll
    for (int r = 0; r < BC; ++r) {
      if (dones[t * BB + b0 + r] > 0) h_lds[r][tid] = 0.f;
    }
    __syncthreads();

    // stage 2: sf = leakyrelu(x @ W1^T + b1), thread computes column tid for 4 rows
    {
      float a0 = b1v, a1 = b1v, a2 = b1v, a3 = b1v;
      for (int k = 0; k < FF; ++k) {
        float w = W1T[k * HH + tid];
        a0 = fmaf(x_lds[0][k], w, a0);
        a1 = fmaf(x_lds[1][k], w, a1);
        a2 = fmaf(x_lds[2][k], w, a2);
        a3 = fmaf(x_lds[3][k], w, a3);
      }
      sf_lds[0][tid] = a0 >= 0.f ? a0 : 0.01f * a0;
      sf_lds[1][tid] = a1 >= 0.f ? a1 : 0.01f * a1;
      sf_lds[2][tid] = a2 >= 0.f ? a2 : 0.01f * a2;
      sf_lds[3][tid] = a3 >= 0.f ? a3 : 0.01f * a3;
    }
    __syncthreads();

    // stage 3: K-loop — gi + gh for this thread's three gate columns (tid, H+tid, 2H+tid)
    float ar[BC], az[BC], gin[BC], ghn[BC];
#pragma unroll
    for (int r = 0; r < BC; ++r) {
      ar[r] = bih_r + bhh_r; az[r] = bih_z + bhh_z;
      gin[r] = bih_n;        ghn[r] = bhh_n;
    }
    for (int k = 0; k < HH; k += 4) {
      float sfv[BC][4], hv[BC][4];
#pragma unroll
      for (int r = 0; r < BC; ++r) {
        float4 s = *(const float4*)&sf_lds[r][k];
        float4 h4 = *(const float4*)&h_lds[r][k];
        sfv[r][0]=s.x; sfv[r][1]=s.y; sfv[r][2]=s.z; sfv[r][3]=s.w;
        hv[r][0]=h4.x; hv[r][1]=h4.y; hv[r][2]=h4.z; hv[r][3]=h4.w;
      }
#pragma unroll
      for (int u = 0; u < 4; ++u) {
        const float* wi = &WihT[(k + u) * 768 + tid];
        const float* wh = &WhhT[(k + u) * 768 + tid];
        float wir = wi[0], wiz = wi[256], win = wi[512];
        float whr = wh[0], whz = wh[256], whn = wh[512];
#pragma unroll
        for (int r = 0; r < BC; ++r) {
          ar[r]  = fmaf(sfv[r][u], wir, ar[r]);
          ar[r]  = fmaf(hv[r][u],  whr, ar[r]);
          az[r]  = fmaf(sfv[r][u], wiz, az[r]);
          az[r]  = fmaf(hv[r][u],  whz, az[r]);
          gin[r] = fmaf(sfv[r][u], win, gin[r]);
          ghn[r] = fmaf(hv[r][u],  whn, ghn[r]);
        }
      }
    }
    __syncthreads();   // all K-loop reads of h_lds done before overwriting

    // stage 4: gates + state update (owner column)
#pragma unroll
    for (int r = 0; r < BC; ++r) {
      float rg = 1.f / (1.f + expf(-ar[r]));
      float zg = 1.f / (1.f + expf(-az[r]));
      float nv = tanhf(gin[r] + rg * ghn[r]);
      h_lds[r][tid] = (1.f - zg) * nv + zg * h_lds[r][tid];
    }
    __syncthreads();
  }

  // heads on h_final (= outs[-1]): means [1,B,A] | stds [1,B,A] | hidden [1,B,H]
  if (tid < BC * AA) {
    int r = tid >> 3, a = tid & 7;
    float macc = bm[a], sacc = bs[a];
    for (int k = 0; k < HH; ++k) {
      float hv = h_lds[r][k];
      macc = fmaf(hv, Wm[a * HH + k], macc);
      sacc = fmaf(hv, Wsw[a * HH + k], sacc);
    }
    int b = b0 + r;
    out[b * AA + a] = tanhf(macc);
    float sp = fmaxf(sacc, 0.f) + log1pf(expf(-fabsf(sacc)));
    out[BB * AA + b * AA + a] = fmaxf(sp, 1e-5f);
  }
#pragma unroll
  for (int r = 0; r < BC; ++r)
    out[2 * BB * AA + (b0 + r) * HH + tid] = h_lds[r][tid];
}

extern "C" void kernel_launch(void* const* d_in, const int* in_sizes, int n_in,
                              void* d_out, int out_size, void* d_ws, size_t ws_size,
                              hipStream_t stream) {
  const float* x    = (const float*)d_in[0];
  const int*   dn   = (const int*)  d_in[1];
  const float* W1   = (const float*)d_in[2];
  const float* b1   = (const float*)d_in[3];
  const float* W_ih = (const float*)d_in[4];
  const float* W_hh = (const float*)d_in[5];
  const float* b_ih = (const float*)d_in[6];
  const float* b_hh = (const float*)d_in[7];
  const float* Wm   = (const float*)d_in[8];
  const float* bm   = (const float*)d_in[9];
  const float* Wsw  = (const float*)d_in[10];
  const float* bs   = (const float*)d_in[11];
  float* out = (float*)d_out;
  float* wsf = (float*)d_ws;

  // transpose W1, W_ih, W_hh into k-major layouts in ws (1.64 MB)
  int total = FF * HH + 2 * HH * 3 * HH;          // 409600
  transpose_weights<<<(total + 255) / 256, 256, 0, stream>>>(W1, W_ih, W_hh, wsf);
  gru_seq<<<NWG, 256, 0, stream>>>(x, dn, b1, b_ih, b_hh, Wm, bm, Wsw, bs, wsf, out);
}

// Round 2
// 3159.029 us; speedup vs baseline: 3.7859x; 3.7859x over previous
//
#include <hip/hip_runtime.h>
#include <math.h>

typedef __attribute__((ext_vector_type(8))) _Float16 f16x8;
typedef __attribute__((ext_vector_type(4))) float f32x4;

#define TT 512
#define BB 256
#define HH 256
#define AA 8

// ws byte offsets
#define OFF_W1   0u           // 32 tiles  * 1024 B = 32768
#define OFF_WIH  32768u       // 384 tiles * 1024 B = 393216
#define OFF_WHH  425984u      // 384 tiles * 1024 B = 393216
#define OFF_H    819200u      // h_carry fp32 [256][256] = 262144
#define OFF_GI   1081344u     // gi fp32, per (t,bt) tile: 48*4*64*4 = 49152 B

// ---------------- phase 0: pack W1, W_ih, W_hh into fp16 MFMA B-fragments ----
// B[k][j] = W[j][k]; tile (kt,jt): lane l holds 8 elems: j=jt*16+(l&15),
// k=kt*32+(l>>4)*8+e. Same k-mapping is used for all A-fragments, so any
// internal k-permutation cancels in the MFMA contraction.
__global__ __launch_bounds__(256) void prepack(
    const float* __restrict__ W1, const float* __restrict__ Wih,
    const float* __restrict__ Whh, unsigned char* __restrict__ ws) {
  int gid = blockIdx.x * 256 + threadIdx.x;
  int wave = gid >> 6, l = gid & 63;
  const float* src; int K; int tix; size_t dst;
  if (wave < 32)       { src = W1;  K = 64;  tix = wave;       dst = OFF_W1; }
  else if (wave < 416) { src = Wih; K = 256; tix = wave - 32;  dst = OFF_WIH; }
  else                 { src = Whh; K = 256; tix = wave - 416; dst = OFF_WHH; }
  int ntJ = (K == 64) ? 16 : 48;
  int kt = tix / ntJ, jt = tix % ntJ;
  int j = jt * 16 + (l & 15);
  int k = kt * 32 + (l >> 4) * 8;
  const float* p = src + (size_t)j * K + k;
  f16x8 frag;
#pragma unroll
  for (int e = 0; e < 8; ++e) frag[e] = (_Float16)p[e];
  *(f16x8*)(ws + dst + ((size_t)tix * 64 + l) * 16) = frag;
}

// ---------------- phase 1: gi[t][b][768] = leakyrelu(x@W1^T+b1) @ W_ih^T + biases
// One WG per (t, 16-batch tile). 256 thr = 4 waves. x split hi/lo, sf split hi/lo.
// gi stored fp32 in D-fragment order: [jt 0..47][reg 0..3][lane16 0..63].
__global__ __launch_bounds__(256) void gru_gi(
    const float* __restrict__ x, const float* __restrict__ b1,
    const float* __restrict__ b_ih, const float* __restrict__ b_hh,
    const unsigned char* __restrict__ wsro, unsigned char* __restrict__ giout,
    int t0) {
  __shared__ __align__(16) _Float16 sfh[16 * 256];
  __shared__ __align__(16) _Float16 sfl[16 * 256];
  __shared__ __align__(16) unsigned char gis[49152];
  int tid = threadIdx.x, w = tid >> 6, l = tid & 63;
  int tl = blockIdx.x >> 4, bt = blockIdx.x & 15;
  int t = t0 + tl;
  int row = l & 15, kg = l >> 4;

  // ---- sf GEMM: [16 x 64] @ [64 x 256]
  f32x4 sacc[4] = {{0.f,0.f,0.f,0.f},{0.f,0.f,0.f,0.f},{0.f,0.f,0.f,0.f},{0.f,0.f,0.f,0.f}};
  const f16x8* pW1 = (const f16x8*)(wsro + OFF_W1);
  size_t xbase = ((size_t)t * BB + bt * 16 + row) * 64;
#pragma unroll
  for (int kt = 0; kt < 2; ++kt) {
    float4 p0 = *(const float4*)(x + xbase + kt * 32 + kg * 8);
    float4 p1 = *(const float4*)(x + xbase + kt * 32 + kg * 8 + 4);
    float xv[8] = {p0.x, p0.y, p0.z, p0.w, p1.x, p1.y, p1.z, p1.w};
    f16x8 xh, xl;
#pragma unroll
    for (int e = 0; e < 8; ++e) {
      _Float16 h = (_Float16)xv[e];
      xh[e] = h; xl[e] = (_Float16)(xv[e] - (float)h);
    }
#pragma unroll
    for (int jj = 0; jj < 4; ++jj) {
      f16x8 bw = pW1[(kt * 16 + w * 4 + jj) * 64 + l];
      sacc[jj] = __builtin_amdgcn_mfma_f32_16x16x32_f16(xh, bw, sacc[jj], 0, 0, 0);
      sacc[jj] = __builtin_amdgcn_mfma_f32_16x16x32_f16(xl, bw, sacc[jj], 0, 0, 0);
    }
  }
#pragma unroll
  for (int jj = 0; jj < 4; ++jj) {
    int j = (w * 4 + jj) * 16 + row;     // sf column
    float b1v = b1[j];
#pragma unroll
    for (int rg = 0; rg < 4; ++rg) {
      int rr = kg * 4 + rg;              // sf row
      float v = sacc[jj][rg] + b1v;
      v = v >= 0.f ? v : 0.01f * v;
      _Float16 hi = (_Float16)v;
      _Float16 lo = (_Float16)(v - (float)hi);
      int byt = (j * 2) ^ ((rr & 7) << 4);
      *(_Float16*)((char*)sfh + rr * 512 + byt) = hi;
      *(_Float16*)((char*)sfl + rr * 512 + byt) = lo;
    }
  }
  __syncthreads();

  // ---- gi GEMM: [16 x 256] @ [256 x 768], wave w owns jt = w*12 .. w*12+11
  f32x4 g[12];
#pragma unroll
  for (int jj = 0; jj < 12; ++jj) g[jj] = (f32x4){0.f, 0.f, 0.f, 0.f};
  const f16x8* pWih = (const f16x8*)(wsro + OFF_WIH);
  for (int kt = 0; kt < 8; ++kt) {
    int rb = row * 512 + ((kt * 64 + kg * 16) ^ ((row & 7) << 4));
    f16x8 ah = *(const f16x8*)((const char*)sfh + rb);
    f16x8 al = *(const f16x8*)((const char*)sfl + rb);
#pragma unroll
    for (int jj = 0; jj < 12; ++jj) {
      f16x8 bw = pWih[((size_t)(kt * 48 + w * 12 + jj)) * 64 + l];
      g[jj] = __builtin_amdgcn_mfma_f32_16x16x32_f16(ah, bw, g[jj], 0, 0, 0);
      g[jj] = __builtin_amdgcn_mfma_f32_16x16x32_f16(al, bw, g[jj], 0, 0, 0);
    }
  }
#pragma unroll
  for (int jj = 0; jj < 12; ++jj) {
    int jt = w * 12 + jj;
    int j = jt * 16 + row;               // gate column 0..767
    float bias = b_ih[j] + (j < 512 ? b_hh[j] : 0.f);  // b_hh folds for r,z only
#pragma unroll
    for (int rg = 0; rg < 4; ++rg)
      *(float*)(gis + jt * 1024 + rg * 256 + l * 4) = g[jj][rg] + bias;
  }
  __syncthreads();

  size_t gbase = (size_t)(tl * 16 + bt) * 49152;
#pragma unroll
  for (int i = 0; i < 12; ++i) {
    int off = (i * 256 + tid) * 16;
    *(float4*)(giout + gbase + off) = *(const float4*)(gis + off);
  }
}

// ---------------- phase 2: sequential GRU, 16 WGs (Bc=16) x 512 thr (8 waves)
// W_hh register-resident as fp16 fragments; h carried as fp32 regs + hi/lo fp16 LDS.
__global__ __launch_bounds__(512) void gru_seq(
    const int* __restrict__ dones, const float* __restrict__ b_hh,
    const float* __restrict__ Wm, const float* __restrict__ bm,
    const float* __restrict__ Wsv, const float* __restrict__ bsv,
    const unsigned char* __restrict__ wsro, unsigned char* __restrict__ hcar,
    const unsigned char* __restrict__ gi, int t0, int tch,
    float* __restrict__ out) {
  __shared__ __align__(16) _Float16 hhi[16 * 256];
  __shared__ __align__(16) _Float16 hlo[16 * 256];
  __shared__ __align__(16) unsigned char ghl[48 * 1040];  // [jt][lane16][reg], +16B pad/tile
  int tid = threadIdx.x, w = tid >> 6, l = tid & 63;
  int bt = blockIdx.x;
  int row = l & 15, kg = l >> 4;

  // W_hh fragments: wave w owns jt = w*6 .. w*6+5 (96 gate cols), all 8 ktiles
  f16x8 whh[6][8];
  const f16x8* pWhh = (const f16x8*)(wsro + OFF_WHH);
#pragma unroll
  for (int jj = 0; jj < 6; ++jj)
#pragma unroll
    for (int kt = 0; kt < 8; ++kt)
      whh[jj][kt] = pWhh[(size_t)(kt * 48 + w * 6 + jj) * 64 + l];

  // update-role mapping: thread owns h[rr][c0..c0+7]
  int rr = tid >> 5;
  int c0 = (tid & 31) * 8;
  float hreg[8];
  {
    const float* hc = (const float*)hcar + (bt * 16 + rr) * 256 + c0;
    f16x8 hh, hl;
#pragma unroll
    for (int ci = 0; ci < 8; ++ci) {
      hreg[ci] = hc[ci];
      _Float16 h = (_Float16)hreg[ci];
      hh[ci] = h; hl[ci] = (_Float16)(hreg[ci] - (float)h);
    }
    int byt = (c0 * 2) ^ ((rr & 7) << 4);
    *(f16x8*)((char*)hhi + rr * 512 + byt) = hh;
    *(f16x8*)((char*)hlo + rr * 512 + byt) = hl;
  }
  __syncthreads();

  for (int tl = 0; tl < tch; ++tl) {
    int t = t0 + tl;
    // ---- MFMA: gh = h @ W_hh^T (split h = hi + lo)
    f32x4 acc[6];
#pragma unroll
    for (int jj = 0; jj < 6; ++jj) acc[jj] = (f32x4){0.f, 0.f, 0.f, 0.f};
#pragma unroll
    for (int kt = 0; kt < 8; ++kt) {
      int rb = row * 512 + ((kt * 64 + kg * 16) ^ ((row & 7) << 4));
      f16x8 ah = *(const f16x8*)((const char*)hhi + rb);
      f16x8 al = *(const f16x8*)((const char*)hlo + rb);
#pragma unroll
      for (int jj = 0; jj < 6; ++jj) {
        acc[jj] = __builtin_amdgcn_mfma_f32_16x16x32_f16(ah, whh[jj][kt], acc[jj], 0, 0, 0);
        acc[jj] = __builtin_amdgcn_mfma_f32_16x16x32_f16(al, whh[jj][kt], acc[jj], 0, 0, 0);
      }
    }
#pragma unroll
    for (int jj = 0; jj < 6; ++jj)
      *(f32x4*)(ghl + (w * 6 + jj) * 1040 + l * 16) = acc[jj];

    // ---- issue gi / bias / dones loads (overlap with other waves' MFMA tail)
    const char* gt = (const char*)gi + (size_t)(tl * 16 + bt) * 49152;
    float gf[3][8];
#pragma unroll
    for (int gg = 0; gg < 3; ++gg) {
      int jt = gg * 16 + (c0 >> 4);
      int ob = jt * 1024 + (rr & 3) * 256 + ((rr >> 2) * 16 + (c0 & 15)) * 4;
      float4 a = *(const float4*)(gt + ob);
      float4 b = *(const float4*)(gt + ob + 16);
      gf[gg][0]=a.x; gf[gg][1]=a.y; gf[gg][2]=a.z; gf[gg][3]=a.w;
      gf[gg][4]=b.x; gf[gg][5]=b.y; gf[gg][6]=b.z; gf[gg][7]=b.w;
    }
    float4 bn0 = *(const float4*)(b_hh + 512 + c0);
    float4 bn1 = *(const float4*)(b_hh + 512 + c0 + 4);
    float bn[8] = {bn0.x,bn0.y,bn0.z,bn0.w,bn1.x,bn1.y,bn1.z,bn1.w};
    int dn = (t < TT - 1) ? dones[(t + 1) * BB + bt * 16 + rr] : 0;
    __syncthreads();

    // ---- update: thread owns rows rr, cols c0..c0+7
    int lane16b = ((rr >> 2) * 16 + (c0 & 15)) * 16 + (rr & 3) * 4;
    int jtb = (c0 >> 4) * 1040;
    f16x8 hh, hl;
#pragma unroll
    for (int ci = 0; ci < 8; ++ci) {
      float ghr = *(const float*)(ghl + jtb            + lane16b + ci * 16);
      float ghz = *(const float*)(ghl + jtb + 16*1040  + lane16b + ci * 16);
      float ghn = *(const float*)(ghl + jtb + 32*1040  + lane16b + ci * 16);
      float rg = 1.f / (1.f + expf(-(gf[0][ci] + ghr)));
      float zg = 1.f / (1.f + expf(-(gf[1][ci] + ghz)));
      float ng = tanhf(gf[2][ci] + rg * (ghn + bn[ci]));
      float hnew = (1.f - zg) * ng + zg * hreg[ci];
      hreg[ci] = dn > 0 ? 0.f : hnew;
      _Float16 h = (_Float16)hreg[ci];
      hh[ci] = h; hl[ci] = (_Float16)(hreg[ci] - (float)h);
    }
    int byt = (c0 * 2) ^ ((rr & 7) << 4);
    *(f16x8*)((char*)hhi + rr * 512 + byt) = hh;
    *(f16x8*)((char*)hlo + rr * 512 + byt) = hl;
    __syncthreads();
  }

  // carry h to next chunk
  {
    float* hc = (float*)hcar + (bt * 16 + rr) * 256 + c0;
#pragma unroll
    for (int ci = 0; ci < 8; ++ci) hc[ci] = hreg[ci];
  }

  if (t0 + tch == TT) {
    // hidden: out[4096 + b*256 + c]
#pragma unroll
    for (int ci = 0; ci < 8; ++ci)
      out[2 * BB * AA + (bt * 16 + rr) * 256 + c0 + ci] = hreg[ci];
    // heads on h_final
    if (tid < 256) {
      int r2 = tid >> 4, a = (tid >> 1) & 7, hd = tid & 1;
      const float* W = hd ? Wsv : Wm;
      float acc2 = 0.f;
      for (int k = 0; k < 256; k += 8) {
        int byt2 = (k * 2) ^ ((r2 & 7) << 4);
        f16x8 vh = *(const f16x8*)((const char*)hhi + r2 * 512 + byt2);
        f16x8 vl = *(const f16x8*)((const char*)hlo + r2 * 512 + byt2);
#pragma unroll
        for (int e = 0; e < 8; ++e)
          acc2 += ((float)vh[e] + (float)vl[e]) * W[a * 256 + k + e];
      }
      int b = bt * 16 + r2;
      if (hd == 0) {
        out[b * AA + a] = tanhf(acc2 + bm[a]);
      } else {
        float v = acc2 + bsv[a];
        float sp = fmaxf(v, 0.f) + log1pf(expf(-fabsf(v)));
        out[BB * AA + b * AA + a] = fmaxf(sp, 1e-5f);
      }
    }
  }
}

extern "C" void kernel_launch(void* const* d_in, const int* in_sizes, int n_in,
                              void* d_out, int out_size, void* d_ws, size_t ws_size,
                              hipStream_t stream) {
  const float* x    = (const float*)d_in[0];
  const int*   dn   = (const int*)  d_in[1];
  const float* W1   = (const float*)d_in[2];
  const float* b1   = (const float*)d_in[3];
  const float* W_ih = (const float*)d_in[4];
  const float* W_hh = (const float*)d_in[5];
  const float* b_ih = (const float*)d_in[6];
  const float* b_hh = (const float*)d_in[7];
  const float* Wm   = (const float*)d_in[8];
  const float* bm   = (const float*)d_in[9];
  const float* Wsv  = (const float*)d_in[10];
  const float* bs   = (const float*)d_in[11];
  float* out = (float*)d_out;
  unsigned char* ws = (unsigned char*)d_ws;

  // pick largest chunk of timesteps whose gi buffer fits in ws
  int tch = TT;
  while (tch > 1 && (size_t)OFF_GI + (size_t)tch * 16 * 49152 > ws_size) tch >>= 1;

  prepack<<<200, 256, 0, stream>>>(W1, W_ih, W_hh, ws);
  hipMemsetAsync(ws + OFF_H, 0, 262144, stream);
  for (int t0 = 0; t0 < TT; t0 += tch) {
    gru_gi<<<dim3(tch * 16), 256, 0, stream>>>(x, b1, b_ih, b_hh, ws, ws + OFF_GI, t0);
    gru_seq<<<16, 512, 0, stream>>>(dn, b_hh, Wm, bm, Wsv, bs, ws, ws + OFF_H,
                                    ws + OFF_GI, t0, tch, out);
  }
}

// Round 3
// 2395.940 us; speedup vs baseline: 4.9917x; 1.3185x over previous
//
#include <hip/hip_runtime.h>
#include <math.h>

typedef __attribute__((ext_vector_type(8))) _Float16 f16x8;
typedef __attribute__((ext_vector_type(4))) float f32x4;

#define TT 512
#define BB 256
#define HH 256
#define AA 8

// ws byte offsets
#define OFF_W1   0u           // 32 tiles  * 1024 B
#define OFF_WIH  32768u       // 384 tiles * 1024 B
#define OFF_WHH  425984u      // 384 tiles * 1024 B
#define OFF_H    819200u      // h_carry fp32 [256][256]
#define OFF_GI   1081344u     // gi fp32, per (t,bt): 48*64*4*4 = 49152 B

__device__ inline float fexp2(float x) { return __builtin_amdgcn_exp2f(x); }
__device__ inline float frcp(float x)  { return __builtin_amdgcn_rcpf(x); }
__device__ inline float fsigm(float x) { return frcp(1.f + fexp2(x * -1.4426950408889634f)); }
__device__ inline float ftanh_(float x){ return 1.f - 2.f * frcp(1.f + fexp2(x * 2.8853900817779268f)); }
// h LDS swizzle: XOR byte bits 4-7 with bit-swapped row (kg into low bits -> write-conflict-free)
__device__ inline int hswz(int r) { return (((r >> 2) & 3) | ((r & 3) << 2)) << 4; }

// ---------------- phase 0: pack weights into fp16 MFMA B-fragments ----------
// Gate-permuted tiles for Wih/Whh: jtn = blk*3 + g  (orig col j = g*256+blk*16+col16)
__global__ __launch_bounds__(256) void prepack(
    const float* __restrict__ W1, const float* __restrict__ Wih,
    const float* __restrict__ Whh, unsigned char* __restrict__ ws) {
  int gid = blockIdx.x * 256 + threadIdx.x;
  int wave = gid >> 6, l = gid & 63;
  const float* src; int K; int tix; size_t dst;
  if (wave < 32)       { src = W1;  K = 64;  tix = wave;       dst = OFF_W1; }
  else if (wave < 416) { src = Wih; K = 256; tix = wave - 32;  dst = OFF_WIH; }
  else                 { src = Whh; K = 256; tix = wave - 416; dst = OFF_WHH; }
  int ntJ = (K == 64) ? 16 : 48;
  int kt = tix / ntJ, jt = tix % ntJ;
  int j;
  if (K == 64) j = jt * 16 + (l & 15);
  else { int g = jt % 3, blk = jt / 3; j = g * 256 + blk * 16 + (l & 15); }
  int k = kt * 32 + (l >> 4) * 8;
  const float* p = src + (size_t)j * K + k;
  f16x8 frag;
#pragma unroll
  for (int e = 0; e < 8; ++e) frag[e] = (_Float16)p[e];
  *(f16x8*)(ws + dst + ((size_t)tix * 64 + l) * 16) = frag;
}

// ---------------- phase 1: gi = leakyrelu(x@W1^T+b1) @ W_ih^T + folded biases
// Output layout per (t,bt): [jtn 0..47][lane 0..63][reg 0..3] fp32 (f32x4/lane)
__global__ __launch_bounds__(256) void gru_gi(
    const float* __restrict__ x, const float* __restrict__ b1,
    const float* __restrict__ b_ih, const float* __restrict__ b_hh,
    const unsigned char* __restrict__ wsro, unsigned char* __restrict__ giout,
    int t0) {
  __shared__ __align__(16) _Float16 sfh[16 * 256];
  __shared__ __align__(16) _Float16 sfl[16 * 256];
  __shared__ __align__(16) unsigned char gis[49152];
  int tid = threadIdx.x, w = tid >> 6, l = tid & 63;
  int tl = blockIdx.x >> 4, bt = blockIdx.x & 15;
  int t = t0 + tl;
  int row = l & 15, kg = l >> 4;

  // sf GEMM: [16 x 64] @ [64 x 256], x split hi/lo
  f32x4 sacc[4] = {{0.f,0.f,0.f,0.f},{0.f,0.f,0.f,0.f},{0.f,0.f,0.f,0.f},{0.f,0.f,0.f,0.f}};
  const f16x8* pW1 = (const f16x8*)(wsro + OFF_W1);
  size_t xbase = ((size_t)t * BB + bt * 16 + row) * 64;
#pragma unroll
  for (int kt = 0; kt < 2; ++kt) {
    float4 p0 = *(const float4*)(x + xbase + kt * 32 + kg * 8);
    float4 p1 = *(const float4*)(x + xbase + kt * 32 + kg * 8 + 4);
    float xv[8] = {p0.x, p0.y, p0.z, p0.w, p1.x, p1.y, p1.z, p1.w};
    f16x8 xh, xl;
#pragma unroll
    for (int e = 0; e < 8; ++e) {
      _Float16 h = (_Float16)xv[e];
      xh[e] = h; xl[e] = (_Float16)(xv[e] - (float)h);
    }
#pragma unroll
    for (int jj = 0; jj < 4; ++jj) {
      f16x8 bw = pW1[(kt * 16 + w * 4 + jj) * 64 + l];
      sacc[jj] = __builtin_amdgcn_mfma_f32_16x16x32_f16(xh, bw, sacc[jj], 0, 0, 0);
      sacc[jj] = __builtin_amdgcn_mfma_f32_16x16x32_f16(xl, bw, sacc[jj], 0, 0, 0);
    }
  }
#pragma unroll
  for (int jj = 0; jj < 4; ++jj) {
    int j = (w * 4 + jj) * 16 + row;     // sf column
    float b1v = b1[j];
#pragma unroll
    for (int rg = 0; rg < 4; ++rg) {
      int rr = kg * 4 + rg;              // sf row (batch)
      float v = sacc[jj][rg] + b1v;
      v = v >= 0.f ? v : 0.01f * v;
      _Float16 hi = (_Float16)v;
      _Float16 lo = (_Float16)(v - (float)hi);
      int byt = (j * 2) ^ ((rr & 7) << 4);
      *(_Float16*)((char*)sfh + rr * 512 + byt) = hi;
      *(_Float16*)((char*)sfl + rr * 512 + byt) = lo;
    }
  }
  __syncthreads();

  // gi GEMM: [16 x 256] @ [256 x 768] over permuted tiles; wave owns jtn w*12..w*12+11
  f32x4 gacc[12];
#pragma unroll
  for (int jj = 0; jj < 12; ++jj) gacc[jj] = (f32x4){0.f, 0.f, 0.f, 0.f};
  const f16x8* pWih = (const f16x8*)(wsro + OFF_WIH);
  for (int kt = 0; kt < 8; ++kt) {
    int rb = row * 512 + ((kt * 64 + kg * 16) ^ ((row & 7) << 4));
    f16x8 ah = *(const f16x8*)((const char*)sfh + rb);
    f16x8 al = *(const f16x8*)((const char*)sfl + rb);
#pragma unroll
    for (int jj = 0; jj < 12; ++jj) {
      f16x8 bw = pWih[((size_t)(kt * 48 + w * 12 + jj)) * 64 + l];
      gacc[jj] = __builtin_amdgcn_mfma_f32_16x16x32_f16(ah, bw, gacc[jj], 0, 0, 0);
      gacc[jj] = __builtin_amdgcn_mfma_f32_16x16x32_f16(al, bw, gacc[jj], 0, 0, 0);
    }
  }
#pragma unroll
  for (int jj = 0; jj < 12; ++jj) {
    int jt = w * 12 + jj;                // permuted tile index
    int g = jt % 3, blk = jt / 3;
    int j = g * 256 + blk * 16 + row;    // original gate column
    float bias = b_ih[j] + (g < 2 ? b_hh[j] : 0.f);
    f32x4 gw = gacc[jj] + bias;
    *(f32x4*)(gis + ((jt * 64 + l) << 4)) = gw;
  }
  __syncthreads();

  size_t gbase = (size_t)(tl * 16 + bt) * 49152;
#pragma unroll
  for (int i = 0; i < 12; ++i) {
    int off = (i * 256 + tid) * 16;
    *(float4*)(giout + gbase + off) = *(const float4*)(gis + off);
  }
}

// ---------------- phase 2: sequential GRU, 16 WGs x 512 thr (8 waves) --------
// W_hh register-resident; update on in-register D-fragments; 1 barrier/step.
__global__ __launch_bounds__(512, 2) void gru_seq(
    const int* __restrict__ dones, const float* __restrict__ b_hh,
    const float* __restrict__ Wm, const float* __restrict__ bm,
    const float* __restrict__ Wsv, const float* __restrict__ bsv,
    const unsigned char* __restrict__ wsro, unsigned char* __restrict__ hcar,
    const unsigned char* __restrict__ gi, int t0, int tch,
    float* __restrict__ out) {
  __shared__ __align__(16) _Float16 hbuf[2][16 * 256];   // 16 KB
  __shared__ int dnl[128 * 16];                          // 8 KB
  int tid = threadIdx.x, w = tid >> 6, l = tid & 63;
  int bt = blockIdx.x;
  int row = l & 15, kg = l >> 4;

  // W_hh fragments: wave w owns jtn = 6w..6w+5 = blocks {2w,2w+1} x gates {r,z,n}
  f16x8 whh[6][8];
  const f16x8* pWhh = (const f16x8*)(wsro + OFF_WHH);
#pragma unroll
  for (int jj = 0; jj < 6; ++jj)
#pragma unroll
    for (int kt = 0; kt < 8; ++kt)
      whh[jj][kt] = pWhh[(size_t)(kt * 48 + 6 * w + jj) * 64 + l];

  // thread's 8 h positions: (row r = kg*4+rg, col c = (2w+b)*16+row)
  float h_old[2][4];
  float bn[2];
#pragma unroll
  for (int b = 0; b < 2; ++b) {
    int c = (2 * w + b) * 16 + row;
    bn[b] = b_hh[512 + c];
#pragma unroll
    for (int rg = 0; rg < 4; ++rg) {
      int r = kg * 4 + rg;
      float hv = ((const float*)hcar)[(bt * 16 + r) * 256 + c];
      h_old[b][rg] = hv;
      *(_Float16*)((char*)hbuf[0] + r * 512 + ((c * 2) ^ hswz(r))) = (_Float16)hv;
    }
  }
  __syncthreads();

  int p = 0;
  for (int tl = 0; tl < tch; ++tl) {
    if ((tl & 127) == 0) {   // stage next 128 steps of (shifted) dones
      __syncthreads();
      int tb = t0 + tl + 1;
#pragma unroll
      for (int ii = 0; ii < 4; ++ii) {
        int ix = ii * 512 + tid;
        int ti = tb + (ix >> 4);
        dnl[ix] = (ti < TT) ? dones[ti * BB + bt * 16 + (ix & 15)] : 0;
      }
      __syncthreads();
    }

    // gi loads for this step (regs freed by previous update; latency hides under MFMA)
    const unsigned char* gt = gi + (size_t)(tl * 16 + bt) * 49152;
    f32x4 gv[6];
#pragma unroll
    for (int jj = 0; jj < 6; ++jj)
      gv[jj] = *(const f32x4*)(gt + (((6 * w + jj) * 64 + l) << 4));

    // MFMA: gh = h @ W_hh^T (fp16 h, single path)
    f32x4 acc[6];
#pragma unroll
    for (int jj = 0; jj < 6; ++jj) acc[jj] = (f32x4){0.f, 0.f, 0.f, 0.f};
    const char* hb = (const char*)hbuf[p];
#pragma unroll
    for (int kt = 0; kt < 8; ++kt) {
      f16x8 ah = *(const f16x8*)(hb + row * 512 + ((kt * 64 + kg * 16) ^ hswz(row)));
#pragma unroll
      for (int jj = 0; jj < 6; ++jj)
        acc[jj] = __builtin_amdgcn_mfma_f32_16x16x32_f16(ah, whh[jj][kt], acc[jj], 0, 0, 0);
    }

    // update on register fragments
    int dnv[4];
#pragma unroll
    for (int rg = 0; rg < 4; ++rg) dnv[rg] = dnl[(tl & 127) * 16 + kg * 4 + rg];
    char* hw = (char*)hbuf[p ^ 1];
#pragma unroll
    for (int b = 0; b < 2; ++b) {
#pragma unroll
      for (int rg = 0; rg < 4; ++rg) {
        float ar = gv[b * 3 + 0][rg] + acc[b * 3 + 0][rg];
        float az = gv[b * 3 + 1][rg] + acc[b * 3 + 1][rg];
        float rs = fsigm(ar);
        float zs = fsigm(az);
        float ng = ftanh_(gv[b * 3 + 2][rg] + rs * (acc[b * 3 + 2][rg] + bn[b]));
        float hn = ng + zs * (h_old[b][rg] - ng);
        hn = dnv[rg] > 0 ? 0.f : hn;
        h_old[b][rg] = hn;
        int r = kg * 4 + rg, c = (2 * w + b) * 16 + row;
        *(_Float16*)(hw + r * 512 + ((c * 2) ^ hswz(r))) = (_Float16)hn;
      }
    }
    __syncthreads();
    p ^= 1;
  }

  // carry h to next chunk
#pragma unroll
  for (int b = 0; b < 2; ++b)
#pragma unroll
    for (int rg = 0; rg < 4; ++rg)
      ((float*)hcar)[(bt * 16 + kg * 4 + rg) * 256 + (2 * w + b) * 16 + row] = h_old[b][rg];

  if (t0 + tch == TT) {
    // hidden: out[4096 + b*256 + c]
#pragma unroll
    for (int b = 0; b < 2; ++b)
#pragma unroll
      for (int rg = 0; rg < 4; ++rg)
        out[2 * BB * AA + (bt * 16 + kg * 4 + rg) * 256 + (2 * w + b) * 16 + row] = h_old[b][rg];
    // heads on h_final (read fp16 h from LDS)
    if (tid < 256) {
      int r2 = tid >> 4, a = (tid >> 1) & 7, hd = tid & 1;
      const float* W = hd ? Wsv : Wm;
      float acc2 = 0.f;
      const char* hf = (const char*)hbuf[p];
      for (int k = 0; k < 256; k += 8) {
        f16x8 vh = *(const f16x8*)(hf + r2 * 512 + ((k * 2) ^ hswz(r2)));
#pragma unroll
        for (int e = 0; e < 8; ++e)
          acc2 += (float)vh[e] * W[a * 256 + k + e];
      }
      int b = bt * 16 + r2;
      if (hd == 0) {
        out[b * AA + a] = tanhf(acc2 + bm[a]);
      } else {
        float v = acc2 + bsv[a];
        float sp = fmaxf(v, 0.f) + log1pf(expf(-fabsf(v)));
        out[BB * AA + b * AA + a] = fmaxf(sp, 1e-5f);
      }
    }
  }
}

extern "C" void kernel_launch(void* const* d_in, const int* in_sizes, int n_in,
                              void* d_out, int out_size, void* d_ws, size_t ws_size,
                              hipStream_t stream) {
  const float* x    = (const float*)d_in[0];
  const int*   dn   = (const int*)  d_in[1];
  const float* W1   = (const float*)d_in[2];
  const float* b1   = (const float*)d_in[3];
  const float* W_ih = (const float*)d_in[4];
  const float* W_hh = (const float*)d_in[5];
  const float* b_ih = (const float*)d_in[6];
  const float* b_hh = (const float*)d_in[7];
  const float* Wm   = (const float*)d_in[8];
  const float* bm   = (const float*)d_in[9];
  const float* Wsv  = (const float*)d_in[10];
  const float* bs   = (const float*)d_in[11];
  float* out = (float*)d_out;
  unsigned char* ws = (unsigned char*)d_ws;

  // pick largest chunk of timesteps whose gi buffer fits in ws
  int tch = TT;
  while (tch > 1 && (size_t)OFF_GI + (size_t)tch * 16 * 49152 > ws_size) tch >>= 1;

  prepack<<<200, 256, 0, stream>>>(W1, W_ih, W_hh, ws);
  hipMemsetAsync(ws + OFF_H, 0, 262144, stream);
  for (int t0 = 0; t0 < TT; t0 += tch) {
    gru_gi<<<dim3(tch * 16), 256, 0, stream>>>(x, b1, b_ih, b_hh, ws, ws + OFF_GI, t0);
    gru_seq<<<16, 512, 0, stream>>>(dn, b_hh, Wm, bm, Wsv, bs, ws, ws + OFF_H,
                                    ws + OFF_GI, t0, tch, out);
  }
}

// Round 4
// 1308.616 us; speedup vs baseline: 9.1394x; 1.8309x over previous
//
#include <hip/hip_runtime.h>
#include <math.h>

typedef __attribute__((ext_vector_type(8))) _Float16 f16x8;
typedef __attribute__((ext_vector_type(4))) float f32x4;

#define TT 512
#define BB 256
#define HH 256
#define AA 8

// ws byte offsets
#define OFF_W1   0u           // 32 tiles  * 1024 B
#define OFF_WIH  32768u       // 384 tiles * 1024 B
#define OFF_WHH  425984u      // 384 tiles * 1024 B
#define OFF_H    819200u      // h_carry fp32 [256][256]
#define OFF_GI   1081344u     // gi fp32, per (t,bt16): 48*64*4*4 = 49152 B

__device__ inline float fexp2(float x) { return __builtin_amdgcn_exp2f(x); }
__device__ inline float frcp(float x)  { return __builtin_amdgcn_rcpf(x); }
__device__ inline float fsigm(float x) { return frcp(1.f + fexp2(x * -1.4426950408889634f)); }
__device__ inline float ftanh_(float x){ return 1.f - 2.f * frcp(1.f + fexp2(x * 2.8853900817779268f)); }
// h LDS swizzle: XOR byte bits 4-7 with bit-swapped row
__device__ inline int hswz(int r) { return (((r >> 2) & 3) | ((r & 3) << 2)) << 4; }

// async global->LDS, 16B per lane: dest = lds_base + lane*16, src per-lane
__device__ inline void dma16(const void* g, void* l) {
  __builtin_amdgcn_global_load_lds(
      (const __attribute__((address_space(1))) void*)g,
      (__attribute__((address_space(3))) void*)l, 16, 0, 0);
}

// ---------------- phase 0: pack weights into fp16 MFMA B-fragments ----------
// Gate-permuted tiles for Wih/Whh: jtn = blk*3 + g  (orig col j = g*256+blk*16+col16)
__global__ __launch_bounds__(256) void prepack(
    const float* __restrict__ W1, const float* __restrict__ Wih,
    const float* __restrict__ Whh, unsigned char* __restrict__ ws) {
  int gid = blockIdx.x * 256 + threadIdx.x;
  int wave = gid >> 6, l = gid & 63;
  const float* src; int K; int tix; size_t dst;
  if (wave < 32)       { src = W1;  K = 64;  tix = wave;       dst = OFF_W1; }
  else if (wave < 416) { src = Wih; K = 256; tix = wave - 32;  dst = OFF_WIH; }
  else                 { src = Whh; K = 256; tix = wave - 416; dst = OFF_WHH; }
  int ntJ = (K == 64) ? 16 : 48;
  int kt = tix / ntJ, jt = tix % ntJ;
  int j;
  if (K == 64) j = jt * 16 + (l & 15);
  else { int g = jt % 3, blk = jt / 3; j = g * 256 + blk * 16 + (l & 15); }
  int k = kt * 32 + (l >> 4) * 8;
  const float* p = src + (size_t)j * K + k;
  f16x8 frag;
#pragma unroll
  for (int e = 0; e < 8; ++e) frag[e] = (_Float16)p[e];
  *(f16x8*)(ws + dst + ((size_t)tix * 64 + l) * 16) = frag;
}

// ---------------- phase 1: gi = leakyrelu(x@W1^T+b1) @ W_ih^T + folded biases
// Output layout per (t,bt16): [jtn 0..47][lane 0..63][reg 0..3] fp32
__global__ __launch_bounds__(256) void gru_gi(
    const float* __restrict__ x, const float* __restrict__ b1,
    const float* __restrict__ b_ih, const float* __restrict__ b_hh,
    const unsigned char* __restrict__ wsro, unsigned char* __restrict__ giout,
    int t0) {
  __shared__ __align__(16) _Float16 sfh[16 * 256];
  __shared__ __align__(16) _Float16 sfl[16 * 256];
  __shared__ __align__(16) unsigned char gis[49152];
  int tid = threadIdx.x, w = tid >> 6, l = tid & 63;
  int tl = blockIdx.x >> 4, bt = blockIdx.x & 15;
  int t = t0 + tl;
  int row = l & 15, kg = l >> 4;

  // sf GEMM: [16 x 64] @ [64 x 256], x split hi/lo
  f32x4 sacc[4] = {{0.f,0.f,0.f,0.f},{0.f,0.f,0.f,0.f},{0.f,0.f,0.f,0.f},{0.f,0.f,0.f,0.f}};
  const f16x8* pW1 = (const f16x8*)(wsro + OFF_W1);
  size_t xbase = ((size_t)t * BB + bt * 16 + row) * 64;
#pragma unroll
  for (int kt = 0; kt < 2; ++kt) {
    float4 p0 = *(const float4*)(x + xbase + kt * 32 + kg * 8);
    float4 p1 = *(const float4*)(x + xbase + kt * 32 + kg * 8 + 4);
    float xv[8] = {p0.x, p0.y, p0.z, p0.w, p1.x, p1.y, p1.z, p1.w};
    f16x8 xh, xl;
#pragma unroll
    for (int e = 0; e < 8; ++e) {
      _Float16 h = (_Float16)xv[e];
      xh[e] = h; xl[e] = (_Float16)(xv[e] - (float)h);
    }
#pragma unroll
    for (int jj = 0; jj < 4; ++jj) {
      f16x8 bw = pW1[(kt * 16 + w * 4 + jj) * 64 + l];
      sacc[jj] = __builtin_amdgcn_mfma_f32_16x16x32_f16(xh, bw, sacc[jj], 0, 0, 0);
      sacc[jj] = __builtin_amdgcn_mfma_f32_16x16x32_f16(xl, bw, sacc[jj], 0, 0, 0);
    }
  }
#pragma unroll
  for (int jj = 0; jj < 4; ++jj) {
    int j = (w * 4 + jj) * 16 + row;     // sf column
    float b1v = b1[j];
#pragma unroll
    for (int rg = 0; rg < 4; ++rg) {
      int rr = kg * 4 + rg;              // sf row (batch)
      float v = sacc[jj][rg] + b1v;
      v = v >= 0.f ? v : 0.01f * v;
      _Float16 hi = (_Float16)v;
      _Float16 lo = (_Float16)(v - (float)hi);
      int byt = (j * 2) ^ ((rr & 7) << 4);
      *(_Float16*)((char*)sfh + rr * 512 + byt) = hi;
      *(_Float16*)((char*)sfl + rr * 512 + byt) = lo;
    }
  }
  __syncthreads();

  // gi GEMM: [16 x 256] @ [256 x 768] over permuted tiles; wave owns jtn w*12..w*12+11
  f32x4 gacc[12];
#pragma unroll
  for (int jj = 0; jj < 12; ++jj) gacc[jj] = (f32x4){0.f, 0.f, 0.f, 0.f};
  const f16x8* pWih = (const f16x8*)(wsro + OFF_WIH);
  for (int kt = 0; kt < 8; ++kt) {
    int rb = row * 512 + ((kt * 64 + kg * 16) ^ ((row & 7) << 4));
    f16x8 ah = *(const f16x8*)((const char*)sfh + rb);
    f16x8 al = *(const f16x8*)((const char*)sfl + rb);
#pragma unroll
    for (int jj = 0; jj < 12; ++jj) {
      f16x8 bw = pWih[((size_t)(kt * 48 + w * 12 + jj)) * 64 + l];
      gacc[jj] = __builtin_amdgcn_mfma_f32_16x16x32_f16(ah, bw, gacc[jj], 0, 0, 0);
      gacc[jj] = __builtin_amdgcn_mfma_f32_16x16x32_f16(al, bw, gacc[jj], 0, 0, 0);
    }
  }
#pragma unroll
  for (int jj = 0; jj < 12; ++jj) {
    int jt = w * 12 + jj;                // permuted tile index
    int g = jt % 3, blk = jt / 3;
    int j = g * 256 + blk * 16 + row;    // original gate column
    float bias = b_ih[j] + (g < 2 ? b_hh[j] : 0.f);
    f32x4 gw = gacc[jj] + bias;
    *(f32x4*)(gis + ((jt * 64 + l) << 4)) = gw;
  }
  __syncthreads();

  size_t gbase = (size_t)(tl * 16 + bt) * 49152;
#pragma unroll
  for (int i = 0; i < 12; ++i) {
    int off = (i * 256 + tid) * 16;
    *(float4*)(giout + gbase + off) = *(const float4*)(gis + off);
  }
}

// ---------------- phase 2: sequential GRU, 32 WGs (8 batch rows) x 512 thr ---
// W_hh register-resident; gi LDS-prefetched 1 step ahead; lane-compacted update.
__global__ __launch_bounds__(512, 2) void gru_seq(
    const int* __restrict__ dones, const float* __restrict__ b_hh,
    const float* __restrict__ Wm, const float* __restrict__ bm,
    const float* __restrict__ Wsv, const float* __restrict__ bsv,
    const unsigned char* __restrict__ wsro, unsigned char* __restrict__ hcar,
    const unsigned char* __restrict__ gi, int t0, int tch,
    float* __restrict__ out) {
  __shared__ __align__(16) _Float16 hbuf[2][16 * 256];   // 16 KB (rows 8-15 zero)
  __shared__ __align__(16) unsigned char glb[2][24576];  // 48 KB gi double-buffer
  __shared__ int dnl[1024];                              // 4 KB: 128 steps x 8 rows
  int tid = threadIdx.x, w = tid >> 6, u = tid & 63;
  int bt8 = blockIdx.x, bt16 = bt8 >> 1, half = bt8 & 1;
  int row16 = u & 15, kg = u >> 4;                         // A-frag roles
  int col16 = u & 15, rgrp = (u >> 4) & 1, blk = u >> 5;   // update roles
  int c = (2 * w + blk) * 16 + col16;                      // owned h column

  // W_hh fragments: wave w owns jtn = 6w..6w+5 (blocks {2w,2w+1} x gates r,z,n)
  f16x8 whh[6][8];
  const f16x8* pWhh = (const f16x8*)(wsro + OFF_WHH);
#pragma unroll
  for (int jj = 0; jj < 6; ++jj)
#pragma unroll
    for (int kt = 0; kt < 8; ++kt)
      whh[jj][kt] = pWhh[(size_t)(kt * 48 + 6 * w + jj) * 64 + u];

  float bn = b_hh[512 + c];

  // zero rows 8..15 of both h buffers (A-frag reads them; M=8 rows unused)
  {
    int pp = tid >> 8, t2 = tid & 255;
    f16x8 z;
#pragma unroll
    for (int e = 0; e < 8; ++e) z[e] = (_Float16)0.f;
    *(f16x8*)((char*)hbuf[pp] + 4096 + t2 * 16) = z;
  }

  // h_old init + hbuf[0] rows 0..7
  float h_old[4];
#pragma unroll
  for (int rg = 0; rg < 4; ++rg) {
    int rl = rgrp * 4 + rg;
    float hv = ((const float*)hcar)[(bt8 * 8 + rl) * 256 + c];
    h_old[rg] = hv;
    *(_Float16*)((char*)hbuf[0] + rl * 512 + ((c * 2) ^ hswz(rl))) = (_Float16)hv;
  }

  // prologue: DMA gi(t=tl0) into glb[0]
  {
    const unsigned char* gt = gi + (size_t)(0 * 16 + bt16) * 49152;
#pragma unroll
    for (int i = 0; i < 3; ++i) {
      const unsigned char* ga =
          gt + ((size_t)((6 * w + 2 * i + blk) * 64 + half * 32 + (u & 31))) * 16;
      dma16(ga, (char*)glb[0] + (w * 3 + i) * 1024);
    }
  }
  __syncthreads();

  int p = 0, q = 0;
  for (int tl = 0; tl < tch; ++tl) {
    if ((tl & 127) == 0) {   // stage next 128 steps of (shifted) dones
      __syncthreads();
      int tb = t0 + tl + 1;
#pragma unroll
      for (int ii = 0; ii < 2; ++ii) {
        int ix = ii * 512 + tid;
        int ti = tb + (ix >> 3);
        dnl[ix] = (ti < TT) ? dones[ti * BB + bt8 * 8 + (ix & 7)] : 0;
      }
      __syncthreads();
    }

    // issue gi DMA for step tl+1 (lands before next step's barrier drain)
    if (tl + 1 < tch) {
      const unsigned char* gt = gi + (size_t)((tl + 1) * 16 + bt16) * 49152;
#pragma unroll
      for (int i = 0; i < 3; ++i) {
        const unsigned char* ga =
            gt + ((size_t)((6 * w + 2 * i + blk) * 64 + half * 32 + (u & 31))) * 16;
        dma16(ga, (char*)glb[q ^ 1] + (w * 3 + i) * 1024);
      }
    }

    // MFMA: gh = h @ W_hh^T
    f32x4 acc[6];
#pragma unroll
    for (int jj = 0; jj < 6; ++jj) acc[jj] = (f32x4){0.f, 0.f, 0.f, 0.f};
    const char* hb = (const char*)hbuf[p];
#pragma unroll
    for (int kt = 0; kt < 8; ++kt) {
      f16x8 ah = *(const f16x8*)(hb + row16 * 512 + ((kt * 64 + kg * 16) ^ hswz(row16)));
#pragma unroll
      for (int jj = 0; jj < 6; ++jj)
        acc[jj] = __builtin_amdgcn_mfma_f32_16x16x32_f16(ah, whh[jj][kt], acc[jj], 0, 0, 0);
    }

    // gi from LDS (stored-lane m holds jt=6w+2i+(m>>5), inner lane m&31)
    const char* glq = (const char*)glb[q];
    f32x4 gvv[3];
#pragma unroll
    for (int g = 0; g < 3; ++g) {
      int idx3 = 3 * blk + g;
      gvv[g] = *(const f32x4*)(glq + (((w * 3 + (idx3 >> 1)) * 64) +
                                      ((idx3 & 1) * 32 + rgrp * 16 + col16)) * 16);
    }

    // compaction: move block-1 gate sums into lanes 32..63 (all lanes active)
    float av[3][4];
#pragma unroll
    for (int g = 0; g < 3; ++g)
#pragma unroll
      for (int rg = 0; rg < 4; ++rg) {
        float sw = __shfl_xor(acc[3 + g][rg], 32);
        av[g][rg] = (u < 32) ? acc[g][rg] : sw;
      }

    // update: thread owns rows rgrp*4+rg (0..7), col c
    char* hw = (char*)hbuf[p ^ 1];
#pragma unroll
    for (int rg = 0; rg < 4; ++rg) {
      int rl = rgrp * 4 + rg;
      int dn = dnl[(tl & 127) * 8 + rl];
      float rs = fsigm(gvv[0][rg] + av[0][rg]);
      float zs = fsigm(gvv[1][rg] + av[1][rg]);
      float ng = ftanh_(gvv[2][rg] + rs * (av[2][rg] + bn));
      float hn = ng + zs * (h_old[rg] - ng);
      hn = dn > 0 ? 0.f : hn;
      h_old[rg] = hn;
      *(_Float16*)(hw + rl * 512 + ((c * 2) ^ hswz(rl))) = (_Float16)hn;
    }
    __syncthreads();
    p ^= 1; q ^= 1;
  }

  // carry h to next chunk
#pragma unroll
  for (int rg = 0; rg < 4; ++rg)
    ((float*)hcar)[(bt8 * 8 + rgrp * 4 + rg) * 256 + c] = h_old[rg];

  if (t0 + tch == TT) {
    // hidden: out[4096 + b*256 + c]
#pragma unroll
    for (int rg = 0; rg < 4; ++rg)
      out[2 * BB * AA + (bt8 * 8 + rgrp * 4 + rg) * 256 + c] = h_old[rg];
    // heads on h_final (read fp16 h from LDS)
    if (tid < 128) {
      int r2 = tid >> 4, a = (tid >> 1) & 7, hd = tid & 1;
      const float* W = hd ? Wsv : Wm;
      float acc2 = 0.f;
      const char* hf = (const char*)hbuf[p];
      for (int k = 0; k < 256; k += 8) {
        f16x8 vh = *(const f16x8*)(hf + r2 * 512 + ((k * 2) ^ hswz(r2)));
#pragma unroll
        for (int e = 0; e < 8; ++e)
          acc2 += (float)vh[e] * W[a * 256 + k + e];
      }
      int b = bt8 * 8 + r2;
      if (hd == 0) {
        out[b * AA + a] = tanhf(acc2 + bm[a]);
      } else {
        float v = acc2 + bsv[a];
        float sp = fmaxf(v, 0.f) + log1pf(expf(-fabsf(v)));
        out[BB * AA + b * AA + a] = fmaxf(sp, 1e-5f);
      }
    }
  }
}

extern "C" void kernel_launch(void* const* d_in, const int* in_sizes, int n_in,
                              void* d_out, int out_size, void* d_ws, size_t ws_size,
                              hipStream_t stream) {
  const float* x    = (const float*)d_in[0];
  const int*   dn   = (const int*)  d_in[1];
  const float* W1   = (const float*)d_in[2];
  const float* b1   = (const float*)d_in[3];
  const float* W_ih = (const float*)d_in[4];
  const float* W_hh = (const float*)d_in[5];
  const float* b_ih = (const float*)d_in[6];
  const float* b_hh = (const float*)d_in[7];
  const float* Wm   = (const float*)d_in[8];
  const float* bm   = (const float*)d_in[9];
  const float* Wsv  = (const float*)d_in[10];
  const float* bs   = (const float*)d_in[11];
  float* out = (float*)d_out;
  unsigned char* ws = (unsigned char*)d_ws;

  // pick largest chunk of timesteps whose gi buffer fits in ws
  int tch = TT;
  while (tch > 1 && (size_t)OFF_GI + (size_t)tch * 16 * 49152 > ws_size) tch >>= 1;

  prepack<<<200, 256, 0, stream>>>(W1, W_ih, W_hh, ws);
  hipMemsetAsync(ws + OFF_H, 0, 262144, stream);
  for (int t0 = 0; t0 < TT; t0 += tch) {
    gru_gi<<<dim3(tch * 16), 256, 0, stream>>>(x, b1, b_ih, b_hh, ws, ws + OFF_GI, t0);
    gru_seq<<<32, 512, 0, stream>>>(dn, b_hh, Wm, bm, Wsv, bs, ws, ws + OFF_H,
                                    ws + OFF_GI, t0, tch, out);
  }
}

// Round 5
// 1010.175 us; speedup vs baseline: 11.8395x; 1.2954x over previous
//
#include <hip/hip_runtime.h>
#include <math.h>

typedef __attribute__((ext_vector_type(8))) _Float16 f16x8;
typedef __attribute__((ext_vector_type(4))) _Float16 f16x4;
typedef __attribute__((ext_vector_type(4))) float f32x4;

#define TT 512
#define BB 256
#define HH 256
#define AA 8

// ws byte offsets
#define OFF_W1   0u           // 32 tiles  * 1024 B
#define OFF_WIH  32768u       // 384 tiles * 1024 B
#define OFF_WHH  425984u      // 384 tiles * 1024 B
#define OFF_H    819200u      // h_carry fp32 [256][256]
#define OFF_GI   1081344u     // gi fp16, per (t,bt16): 48*64*4*2 = 24576 B

__device__ inline float fexp2(float x) { return __builtin_amdgcn_exp2f(x); }
__device__ inline float frcp(float x)  { return __builtin_amdgcn_rcpf(x); }
__device__ inline float fsigm(float x) { return frcp(1.f + fexp2(x * -1.4426950408889634f)); }
__device__ inline float ftanh_(float x){ return 1.f - 2.f * frcp(1.f + fexp2(x * 2.8853900817779268f)); }
// h LDS swizzle: XOR byte bits 4-7 with bit-swapped row
__device__ inline int hswz(int r) { return (((r >> 2) & 3) | ((r & 3) << 2)) << 4; }

// async global->LDS, 16B per lane: dest = lds_base + lane*16, src per-lane
__device__ inline void dma16(const void* g, void* l) {
  __builtin_amdgcn_global_load_lds(
      (const __attribute__((address_space(1))) void*)g,
      (__attribute__((address_space(3))) void*)l, 16, 0, 0);
}

// ---------------- phase 0: pack weights into fp16 MFMA B-fragments ----------
// Gate-permuted tiles for Wih/Whh: jtn = blk*3 + g  (orig col j = g*256+blk*16+col16)
__global__ __launch_bounds__(256) void prepack(
    const float* __restrict__ W1, const float* __restrict__ Wih,
    const float* __restrict__ Whh, unsigned char* __restrict__ ws) {
  int gid = blockIdx.x * 256 + threadIdx.x;
  int wave = gid >> 6, l = gid & 63;
  const float* src; int K; int tix; size_t dst;
  if (wave < 32)       { src = W1;  K = 64;  tix = wave;       dst = OFF_W1; }
  else if (wave < 416) { src = Wih; K = 256; tix = wave - 32;  dst = OFF_WIH; }
  else                 { src = Whh; K = 256; tix = wave - 416; dst = OFF_WHH; }
  int ntJ = (K == 64) ? 16 : 48;
  int kt = tix / ntJ, jt = tix % ntJ;
  int j;
  if (K == 64) j = jt * 16 + (l & 15);
  else { int g = jt % 3, blk = jt / 3; j = g * 256 + blk * 16 + (l & 15); }
  int k = kt * 32 + (l >> 4) * 8;
  const float* p = src + (size_t)j * K + k;
  f16x8 frag;
#pragma unroll
  for (int e = 0; e < 8; ++e) frag[e] = (_Float16)p[e];
  *(f16x8*)(ws + dst + ((size_t)tix * 64 + l) * 16) = frag;
}

// ---------------- phase 1: gi = leakyrelu(x@W1^T+b1) @ W_ih^T + folded biases
// fp16 output, per (t,bt16): [half 2][jtn 48][lane32 32][reg 4] (8B per lane32)
__global__ __launch_bounds__(256) void gru_gi(
    const float* __restrict__ x, const float* __restrict__ b1,
    const float* __restrict__ b_ih, const float* __restrict__ b_hh,
    const unsigned char* __restrict__ wsro, unsigned char* __restrict__ giout,
    int t0) {
  __shared__ __align__(16) _Float16 sfh[16 * 256];
  int tid = threadIdx.x, w = tid >> 6, l = tid & 63;
  int tl = blockIdx.x >> 4, bt = blockIdx.x & 15;
  int t = t0 + tl;
  int row = l & 15, kg = l >> 4;

  // sf GEMM: [16 x 64] @ [64 x 256], single fp16 path
  f32x4 sacc[4] = {{0.f,0.f,0.f,0.f},{0.f,0.f,0.f,0.f},{0.f,0.f,0.f,0.f},{0.f,0.f,0.f,0.f}};
  const f16x8* pW1 = (const f16x8*)(wsro + OFF_W1);
  size_t xbase = ((size_t)t * BB + bt * 16 + row) * 64;
#pragma unroll
  for (int kt = 0; kt < 2; ++kt) {
    float4 p0 = *(const float4*)(x + xbase + kt * 32 + kg * 8);
    float4 p1 = *(const float4*)(x + xbase + kt * 32 + kg * 8 + 4);
    float xv[8] = {p0.x, p0.y, p0.z, p0.w, p1.x, p1.y, p1.z, p1.w};
    f16x8 xh;
#pragma unroll
    for (int e = 0; e < 8; ++e) xh[e] = (_Float16)xv[e];
#pragma unroll
    for (int jj = 0; jj < 4; ++jj) {
      f16x8 bw = pW1[(kt * 16 + w * 4 + jj) * 64 + l];
      sacc[jj] = __builtin_amdgcn_mfma_f32_16x16x32_f16(xh, bw, sacc[jj], 0, 0, 0);
    }
  }
#pragma unroll
  for (int jj = 0; jj < 4; ++jj) {
    int j = (w * 4 + jj) * 16 + row;     // sf column
    float b1v = b1[j];
#pragma unroll
    for (int rg = 0; rg < 4; ++rg) {
      int rr = kg * 4 + rg;              // sf row (batch)
      float v = sacc[jj][rg] + b1v;
      v = v >= 0.f ? v : 0.01f * v;
      int byt = (j * 2) ^ ((rr & 7) << 4);
      *(_Float16*)((char*)sfh + rr * 512 + byt) = (_Float16)v;
    }
  }
  __syncthreads();

  // gi GEMM: [16 x 256] @ [256 x 768] over permuted tiles; wave owns jtn w*12..w*12+11
  f32x4 gacc[12];
#pragma unroll
  for (int jj = 0; jj < 12; ++jj) gacc[jj] = (f32x4){0.f, 0.f, 0.f, 0.f};
  const f16x8* pWih = (const f16x8*)(wsro + OFF_WIH);
  for (int kt = 0; kt < 8; ++kt) {
    int rb = row * 512 + ((kt * 64 + kg * 16) ^ ((row & 7) << 4));
    f16x8 ah = *(const f16x8*)((const char*)sfh + rb);
#pragma unroll
    for (int jj = 0; jj < 12; ++jj) {
      f16x8 bw = pWih[((size_t)(kt * 48 + w * 12 + jj)) * 64 + l];
      gacc[jj] = __builtin_amdgcn_mfma_f32_16x16x32_f16(ah, bw, gacc[jj], 0, 0, 0);
    }
  }
  unsigned char* gbase = giout + (size_t)(tl * 16 + bt) * 24576 + (l >> 5) * 12288;
#pragma unroll
  for (int jj = 0; jj < 12; ++jj) {
    int jt = w * 12 + jj;                // permuted tile index
    int g = jt % 3, blk = jt / 3;
    int j = g * 256 + blk * 16 + row;    // original gate column
    float bias = b_ih[j] + (g < 2 ? b_hh[j] : 0.f);
    f16x4 o;
#pragma unroll
    for (int rg = 0; rg < 4; ++rg) o[rg] = (_Float16)(gacc[jj][rg] + bias);
    *(f16x4*)(gbase + jt * 256 + (l & 31) * 8) = o;
  }
}

// ---------------- phase 2: sequential GRU, 32 WGs (8 batch rows) x 512 thr ---
// W_hh register-resident; gi fp16, LDS-prefetched 2 steps ahead (counted vmcnt);
// all dones preloaded; lane-compacted update; one raw barrier per step.
__global__ __launch_bounds__(512, 2) void gru_seq(
    const int* __restrict__ dones, const float* __restrict__ b_hh,
    const float* __restrict__ Wm, const float* __restrict__ bm,
    const float* __restrict__ Wsv, const float* __restrict__ bsv,
    const unsigned char* __restrict__ wsro, unsigned char* __restrict__ hcar,
    const unsigned char* __restrict__ gi, int t0, int tch,
    float* __restrict__ out) {
  __shared__ __align__(16) _Float16 hbuf[2][16 * 256];   // 16 KB (rows 8-15 zero)
  __shared__ __align__(16) unsigned char glb[3][12288];  // 36 KB gi triple-buffer
  __shared__ int dnl[512 * 8];                           // 16 KB: whole chunk
  int tid = threadIdx.x, w = tid >> 6, u = tid & 63;
  int bt8 = blockIdx.x, bt16 = bt8 >> 1, half = bt8 & 1;
  int row16 = u & 15, kg = u >> 4;                         // A-frag roles
  int col16 = u & 15, rgrp = (u >> 4) & 1, blk = u >> 5;   // update roles
  int c = (2 * w + blk) * 16 + col16;                      // owned h column

  // W_hh fragments: wave w owns jtn = 6w..6w+5 (blocks {2w,2w+1} x gates r,z,n)
  f16x8 whh[6][8];
  const f16x8* pWhh = (const f16x8*)(wsro + OFF_WHH);
#pragma unroll
  for (int jj = 0; jj < 6; ++jj)
#pragma unroll
    for (int kt = 0; kt < 8; ++kt)
      whh[jj][kt] = pWhh[(size_t)(kt * 48 + 6 * w + jj) * 64 + u];

  float bn = b_hh[512 + c];

  // zero rows 8..15 of both h buffers (A-frag reads them; M=8 rows unused)
  {
    int pp = tid >> 8, t2 = tid & 255;
    f16x8 z;
#pragma unroll
    for (int e = 0; e < 8; ++e) z[e] = (_Float16)0.f;
    *(f16x8*)((char*)hbuf[pp] + 4096 + t2 * 16) = z;
  }

  // h_old init + hbuf[0] rows 0..7
  float h_old[4];
#pragma unroll
  for (int rg = 0; rg < 4; ++rg) {
    int rl = rgrp * 4 + rg;
    float hv = ((const float*)hcar)[(bt8 * 8 + rl) * 256 + c];
    h_old[rg] = hv;
    *(_Float16*)((char*)hbuf[0] + rl * 512 + ((c * 2) ^ hswz(rl))) = (_Float16)hv;
  }

  // preload ALL (shifted) dones for this chunk: dnl[s*8+r] = dones[t0+s+1][bt8*8+r]
#pragma unroll
  for (int ii = 0; ii < 8; ++ii) {
    int ix = ii * 512 + tid;
    if (ix < tch * 8) {
      int ti = t0 + (ix >> 3) + 1;
      dnl[ix] = (ti < TT) ? dones[ti * BB + bt8 * 8 + (ix & 7)] : 0;
    }
  }

  // prologue: DMA gi(t=0) -> glb[0], gi(t=1) -> glb[1]  (waves 0..5, 2 KB each)
  if (w < 6) {
#pragma unroll
    for (int tpre = 0; tpre < 2; ++tpre) {
      int ts = tpre < tch ? tpre : tch - 1;
      const unsigned char* src =
          gi + (size_t)(ts * 16 + bt16) * 24576 + half * 12288 + w * 2048 + (u << 4);
      dma16(src, (char*)glb[tpre] + w * 2048);
      dma16(src + 1024, (char*)glb[tpre] + w * 2048 + 1024);
    }
    asm volatile("s_waitcnt vmcnt(2) lgkmcnt(0)" ::: "memory");
  } else {
    asm volatile("s_waitcnt vmcnt(0) lgkmcnt(0)" ::: "memory");
  }
  __builtin_amdgcn_s_barrier();

  int p = 0, q = 0;
  for (int tl = 0; tl < tch; ++tl) {
    // issue gi DMA for step tl+2 (2-deep pipeline, clamped tail keeps count uniform)
    int qn = q + 2; if (qn >= 3) qn -= 3;
    if (w < 6) {
      int ts = tl + 2 < tch ? tl + 2 : tch - 1;
      const unsigned char* src =
          gi + (size_t)(ts * 16 + bt16) * 24576 + half * 12288 + w * 2048 + (u << 4);
      dma16(src, (char*)glb[qn] + w * 2048);
      dma16(src + 1024, (char*)glb[qn] + w * 2048 + 1024);
    }

    // MFMA: gh = h @ W_hh^T
    f32x4 acc[6];
#pragma unroll
    for (int jj = 0; jj < 6; ++jj) acc[jj] = (f32x4){0.f, 0.f, 0.f, 0.f};
    const char* hb = (const char*)hbuf[p];
#pragma unroll
    for (int kt = 0; kt < 8; ++kt) {
      f16x8 ah = *(const f16x8*)(hb + row16 * 512 + ((kt * 64 + kg * 16) ^ hswz(row16)));
#pragma unroll
      for (int jj = 0; jj < 6; ++jj)
        acc[jj] = __builtin_amdgcn_mfma_f32_16x16x32_f16(ah, whh[jj][kt], acc[jj], 0, 0, 0);
    }

    // gi from LDS: [jtn 48][lane32 32][f16x4]
    const char* glq = (const char*)glb[q];
    float gvv[3][4];
#pragma unroll
    for (int g = 0; g < 3; ++g) {
      int jtn = (2 * w + blk) * 3 + g;
      f16x4 gv = *(const f16x4*)(glq + jtn * 256 + (u & 31) * 8);
#pragma unroll
      for (int rg = 0; rg < 4; ++rg) gvv[g][rg] = (float)gv[rg];
    }

    // compaction: move block-1 gate sums into lanes 32..63 (all lanes active)
    float av[3][4];
#pragma unroll
    for (int g = 0; g < 3; ++g)
#pragma unroll
      for (int rg = 0; rg < 4; ++rg) {
        float sw = __shfl_xor(acc[3 + g][rg], 32);
        av[g][rg] = (u < 32) ? acc[g][rg] : sw;
      }

    // update: thread owns rows rgrp*4+rg (0..7), col c
    char* hw = (char*)hbuf[p ^ 1];
#pragma unroll
    for (int rg = 0; rg < 4; ++rg) {
      int rl = rgrp * 4 + rg;
      int dn = dnl[tl * 8 + rl];
      float rs = fsigm(gvv[0][rg] + av[0][rg]);
      float zs = fsigm(gvv[1][rg] + av[1][rg]);
      float ng = ftanh_(gvv[2][rg] + rs * (av[2][rg] + bn));
      float hn = ng + zs * (h_old[rg] - ng);
      hn = dn > 0 ? 0.f : hn;
      h_old[rg] = hn;
      *(_Float16*)(hw + rl * 512 + ((c * 2) ^ hswz(rl))) = (_Float16)hn;
    }

    // end-of-step: t+1's DMAs must be done (t+2's stay in flight); h writes visible
    if (w < 6) asm volatile("s_waitcnt vmcnt(2) lgkmcnt(0)" ::: "memory");
    else       asm volatile("s_waitcnt vmcnt(0) lgkmcnt(0)" ::: "memory");
    __builtin_amdgcn_s_barrier();
    p ^= 1;
    q = q + 1 < 3 ? q + 1 : 0;
  }

  // carry h to next chunk
#pragma unroll
  for (int rg = 0; rg < 4; ++rg)
    ((float*)hcar)[(bt8 * 8 + rgrp * 4 + rg) * 256 + c] = h_old[rg];

  if (t0 + tch == TT) {
    // hidden: out[4096 + b*256 + c]
#pragma unroll
    for (int rg = 0; rg < 4; ++rg)
      out[2 * BB * AA + (bt8 * 8 + rgrp * 4 + rg) * 256 + c] = h_old[rg];
    // heads on h_final (read fp16 h from LDS)
    if (tid < 128) {
      int r2 = tid >> 4, a = (tid >> 1) & 7, hd = tid & 1;
      const float* W = hd ? Wsv : Wm;
      float acc2 = 0.f;
      const char* hf = (const char*)hbuf[p];
      for (int k = 0; k < 256; k += 8) {
        f16x8 vh = *(const f16x8*)(hf + r2 * 512 + ((k * 2) ^ hswz(r2)));
#pragma unroll
        for (int e = 0; e < 8; ++e)
          acc2 += (float)vh[e] * W[a * 256 + k + e];
      }
      int b = bt8 * 8 + r2;
      if (hd == 0) {
        out[b * AA + a] = tanhf(acc2 + bm[a]);
      } else {
        float v = acc2 + bsv[a];
        float sp = fmaxf(v, 0.f) + log1pf(expf(-fabsf(v)));
        out[BB * AA + b * AA + a] = fmaxf(sp, 1e-5f);
      }
    }
  }
}

extern "C" void kernel_launch(void* const* d_in, const int* in_sizes, int n_in,
                              void* d_out, int out_size, void* d_ws, size_t ws_size,
                              hipStream_t stream) {
  const float* x    = (const float*)d_in[0];
  const int*   dn   = (const int*)  d_in[1];
  const float* W1   = (const float*)d_in[2];
  const float* b1   = (const float*)d_in[3];
  const float* W_ih = (const float*)d_in[4];
  const float* W_hh = (const float*)d_in[5];
  const float* b_ih = (const float*)d_in[6];
  const float* b_hh = (const float*)d_in[7];
  const float* Wm   = (const float*)d_in[8];
  const float* bm   = (const float*)d_in[9];
  const float* Wsv  = (const float*)d_in[10];
  const float* bs   = (const float*)d_in[11];
  float* out = (float*)d_out;
  unsigned char* ws = (unsigned char*)d_ws;

  // pick largest chunk of timesteps whose gi buffer fits in ws
  int tch = TT;
  while (tch > 1 && (size_t)OFF_GI + (size_t)tch * 16 * 24576 > ws_size) tch >>= 1;

  prepack<<<200, 256, 0, stream>>>(W1, W_ih, W_hh, ws);
  hipMemsetAsync(ws + OFF_H, 0, 262144, stream);
  for (int t0 = 0; t0 < TT; t0 += tch) {
    gru_gi<<<dim3(tch * 16), 256, 0, stream>>>(x, b1, b_ih, b_hh, ws, ws + OFF_GI, t0);
    gru_seq<<<32, 512, 0, stream>>>(dn, b_hh, Wm, bm, Wsv, bs, ws, ws + OFF_H,
                                    ws + OFF_GI, t0, tch, out);
  }
}

// Round 7
// 848.922 us; speedup vs baseline: 14.0884x; 1.1900x over previous
//
#include <hip/hip_runtime.h>
#include <math.h>

typedef __attribute__((ext_vector_type(8))) _Float16 f16x8;
typedef __attribute__((ext_vector_type(4))) _Float16 f16x4;
typedef __attribute__((ext_vector_type(4))) float f32x4;

#define TT 512
#define BB 256
#define HH 256
#define AA 8

// ws byte offsets
#define OFF_W1   0u           // 32 tiles  * 1024 B
#define OFF_WIH  32768u       // 384 tiles * 1024 B
#define OFF_WHH  425984u      // 384 tiles * 1024 B
#define OFF_H    819200u      // h_carry fp32 [256][256]
#define OFF_GI   1081344u     // gi fp16, per (t,bt16): 48*64*4*2 = 24576 B
#define GSTRIDE  393216       // gi bytes per timestep (16 bt16 tiles)

__device__ inline float fexp2(float x) { return __builtin_amdgcn_exp2f(x); }
__device__ inline float frcp(float x)  { return __builtin_amdgcn_rcpf(x); }
__device__ inline float fsigm(float x) { return frcp(1.f + fexp2(x * -1.4426950408889634f)); }
__device__ inline float ftanh_(float x){ return 1.f - 2.f * frcp(1.f + fexp2(x * 2.8853900817779268f)); }

// ---------------- phase 0: pack weights into fp16 MFMA B-fragments ----------
__global__ __launch_bounds__(256) void prepack(
    const float* __restrict__ W1, const float* __restrict__ Wih,
    const float* __restrict__ Whh, unsigned char* __restrict__ ws) {
  int gid = blockIdx.x * 256 + threadIdx.x;
  int wave = gid >> 6, l = gid & 63;
  const float* src; int K; int tix; size_t dst;
  if (wave < 32)       { src = W1;  K = 64;  tix = wave;       dst = OFF_W1; }
  else if (wave < 416) { src = Wih; K = 256; tix = wave - 32;  dst = OFF_WIH; }
  else                 { src = Whh; K = 256; tix = wave - 416; dst = OFF_WHH; }
  int ntJ = (K == 64) ? 16 : 48;
  int kt = tix / ntJ, jt = tix % ntJ;
  int j;
  if (K == 64) j = jt * 16 + (l & 15);
  else { int g = jt % 3, blk = jt / 3; j = g * 256 + blk * 16 + (l & 15); }
  int k = kt * 32 + (l >> 4) * 8;
  const float* p = src + (size_t)j * K + k;
  f16x8 frag;
#pragma unroll
  for (int e = 0; e < 8; ++e) frag[e] = (_Float16)p[e];
  *(f16x8*)(ws + dst + ((size_t)tix * 64 + l) * 16) = frag;
}

// ---------------- phase 1: gi = leakyrelu(x@W1^T+b1) @ W_ih^T + folded biases
__global__ __launch_bounds__(256) void gru_gi(
    const float* __restrict__ x, const float* __restrict__ b1,
    const float* __restrict__ b_ih, const float* __restrict__ b_hh,
    const unsigned char* __restrict__ wsro, unsigned char* __restrict__ giout,
    int t0) {
  __shared__ __align__(16) _Float16 sfh[16 * 256];
  int tid = threadIdx.x, w = tid >> 6, l = tid & 63;
  int tl = blockIdx.x >> 4, bt = blockIdx.x & 15;
  int t = t0 + tl;
  int row = l & 15, kg = l >> 4;

  f32x4 sacc[4] = {{0.f,0.f,0.f,0.f},{0.f,0.f,0.f,0.f},{0.f,0.f,0.f,0.f},{0.f,0.f,0.f,0.f}};
  const f16x8* pW1 = (const f16x8*)(wsro + OFF_W1);
  size_t xbase = ((size_t)t * BB + bt * 16 + row) * 64;
#pragma unroll
  for (int kt = 0; kt < 2; ++kt) {
    float4 p0 = *(const float4*)(x + xbase + kt * 32 + kg * 8);
    float4 p1 = *(const float4*)(x + xbase + kt * 32 + kg * 8 + 4);
    float xv[8] = {p0.x, p0.y, p0.z, p0.w, p1.x, p1.y, p1.z, p1.w};
    f16x8 xh;
#pragma unroll
    for (int e = 0; e < 8; ++e) xh[e] = (_Float16)xv[e];
#pragma unroll
    for (int jj = 0; jj < 4; ++jj) {
      f16x8 bw = pW1[(kt * 16 + w * 4 + jj) * 64 + l];
      sacc[jj] = __builtin_amdgcn_mfma_f32_16x16x32_f16(xh, bw, sacc[jj], 0, 0, 0);
    }
  }
#pragma unroll
  for (int jj = 0; jj < 4; ++jj) {
    int j = (w * 4 + jj) * 16 + row;
    float b1v = b1[j];
#pragma unroll
    for (int rg = 0; rg < 4; ++rg) {
      int rr = kg * 4 + rg;
      float v = sacc[jj][rg] + b1v;
      v = v >= 0.f ? v : 0.01f * v;
      int byt = (j * 2) ^ ((rr & 7) << 4);
      *(_Float16*)((char*)sfh + rr * 512 + byt) = (_Float16)v;
    }
  }
  __syncthreads();

  f32x4 gacc[12];
#pragma unroll
  for (int jj = 0; jj < 12; ++jj) gacc[jj] = (f32x4){0.f, 0.f, 0.f, 0.f};
  const f16x8* pWih = (const f16x8*)(wsro + OFF_WIH);
  for (int kt = 0; kt < 8; ++kt) {
    int rb = row * 512 + ((kt * 64 + kg * 16) ^ ((row & 7) << 4));
    f16x8 ah = *(const f16x8*)((const char*)sfh + rb);
#pragma unroll
    for (int jj = 0; jj < 12; ++jj) {
      f16x8 bw = pWih[((size_t)(kt * 48 + w * 12 + jj)) * 64 + l];
      gacc[jj] = __builtin_amdgcn_mfma_f32_16x16x32_f16(ah, bw, gacc[jj], 0, 0, 0);
    }
  }
  unsigned char* gbase = giout + (size_t)(tl * 16 + bt) * 24576 + (l >> 5) * 12288;
#pragma unroll
  for (int jj = 0; jj < 12; ++jj) {
    int jt = w * 12 + jj;
    int g = jt % 3, blk = jt / 3;
    int j = g * 256 + blk * 16 + row;
    float bias = b_ih[j] + (g < 2 ? b_hh[j] : 0.f);
    f16x4 o;
#pragma unroll
    for (int rg = 0; rg < 4; ++rg) o[rg] = (_Float16)(gacc[jj][rg] + bias);
    *(f16x4*)(gbase + jt * 256 + (l & 31) * 8) = o;
  }
}

// ---------------- phase 2: sequential GRU, 32 WGs (8 batch rows) x 512 thr ---
// W_hh register-resident (192 VGPR); gi direct global->reg 1-step prefetch;
// conflict-free K-major swizzled h LDS; shfl_xor compaction; 1 barrier/step.
__global__ __launch_bounds__(512, 2) void gru_seq(
    const int* __restrict__ dones, const float* __restrict__ b_hh,
    const float* __restrict__ Wm, const float* __restrict__ bm,
    const float* __restrict__ Wsv, const float* __restrict__ bsv,
    const unsigned char* __restrict__ wsro, unsigned char* __restrict__ hcar,
    const unsigned char* __restrict__ gi, int t0, int tch,
    float* __restrict__ out) {
  __shared__ __align__(16) unsigned char hbuf[2][8192];  // K-major swizzled h (rows 8-15 zero)
  __shared__ unsigned char dnb[2048];                    // packed dones bytes [step][8 rows]
  int tid = threadIdx.x, w = tid >> 6, u = tid & 63;
  int bt8 = blockIdx.x, bt16 = bt8 >> 1, half = bt8 & 1;
  int row16 = u & 15, kg = u >> 4;                         // A-frag roles
  int col16 = u & 15, rgrp = (u >> 4) & 1, blk = u >> 5;   // update roles
  int c = (2 * w + blk) * 16 + col16;                      // owned h column

  // W_hh fragments: wave w owns jtn = 6w..6w+5 (blocks {2w,2w+1} x gates r,z,n)
  f16x8 whh[6][8];
  const f16x8* pWhh = (const f16x8*)(wsro + OFF_WHH);
#pragma unroll
  for (int jj = 0; jj < 6; ++jj)
#pragma unroll
    for (int kt = 0; kt < 8; ++kt)
      whh[jj][kt] = pWhh[(size_t)(kt * 48 + 6 * w + jj) * 64 + u];

  float bn = b_hh[512 + c];

  // loop-invariant LDS addresses
  int ab0 = (kg * 256 + row16 * 16) ^ (kg << 4);   // A-read base, even kt
  int ab1 = ab0 ^ 64;                              // odd kt
  int ku2 = c >> 3, e2 = c & 7;
  int wbase = (ku2 * 256 + rgrp * 64 + e2 * 2) ^ ((ku2 & 7) << 4);
  const char* hro = (const char*)hbuf;

  // zero rows 8-15 region (upper 128B of each 256B block, both buffers)
  {
    int buf = tid >> 8, r = tid & 255;
    f16x8 z;
#pragma unroll
    for (int e = 0; e < 8; ++e) z[e] = (_Float16)0.f;
    *(f16x8*)((char*)hbuf + buf * 8192 + (r >> 3) * 256 + 128 + (r & 7) * 16) = z;
  }

  // h_old init + hbuf[0] rows 0..7
  float h_old[4];
#pragma unroll
  for (int rg = 0; rg < 4; ++rg) {
    float hv = ((const float*)hcar)[(bt8 * 8 + rgrp * 4 + rg) * 256 + c];
    h_old[rg] = hv;
    *(_Float16*)((char*)hbuf + (wbase ^ (rg << 4))) = (_Float16)hv;
  }

  // preload ALL (shifted) dones for this chunk as bytes
#pragma unroll
  for (int ii = 0; ii < 4; ++ii) {
    int ix = ii * 512 + tid;
    if (ix < tch * 8) {
      int ti = t0 + (ix >> 3) + 1;
      dnb[ix] = (ti < TT) ? (unsigned char)(dones[ti * BB + bt8 * 8 + (ix & 7)] != 0) : (unsigned char)0;
    }
  }

  // gi per-thread pointer (layout matches producer exactly)
  const unsigned char* gpt = gi + (size_t)bt16 * 24576 + half * 12288 +
                             (2 * w + blk) * 768 + (u & 31) * 8;
  f16x4 gA[3], gB[3];
#pragma unroll
  for (int g = 0; g < 3; ++g) gA[g] = *(const f16x4*)(gpt + g * 256);

  asm volatile("s_waitcnt lgkmcnt(0)" ::: "memory");
  __builtin_amdgcn_s_barrier();

#define STEP(TL, P, GC, GN)                                                     \
  {                                                                             \
    int tn = (TL) + 1 < tch ? (TL) + 1 : tch - 1;                               \
    const unsigned char* gpn = gpt + (size_t)tn * GSTRIDE;                      \
    GN[0] = *(const f16x4*)(gpn);                                               \
    GN[1] = *(const f16x4*)(gpn + 256);                                         \
    GN[2] = *(const f16x4*)(gpn + 512);                                         \
    f32x4 acc[6];                                                               \
    _Pragma("unroll") for (int jj = 0; jj < 6; ++jj)                            \
        acc[jj] = (f32x4){0.f, 0.f, 0.f, 0.f};                                  \
    _Pragma("unroll") for (int kt = 0; kt < 8; ++kt) {                          \
      f16x8 ah = *(const f16x8*)(hro + (P) * 8192 + kt * 1024 +                 \
                                 ((kt & 1) ? ab1 : ab0));                       \
      _Pragma("unroll") for (int jj = 0; jj < 6; ++jj)                          \
        acc[jj] = __builtin_amdgcn_mfma_f32_16x16x32_f16(ah, whh[jj][kt],       \
                                                         acc[jj], 0, 0, 0);     \
    }                                                                           \
    int dn4 = *(const int*)(dnb + (TL) * 8 + rgrp * 4);                         \
    char* hw = (char*)hbuf + ((P) ^ 1) * 8192;                                  \
    _Pragma("unroll") for (int rg = 0; rg < 4; ++rg) {                          \
      float swr = __shfl_xor(acc[3][rg], 32);                                   \
      float swz = __shfl_xor(acc[4][rg], 32);                                   \
      float swn = __shfl_xor(acc[5][rg], 32);                                   \
      float avr = (u < 32) ? acc[0][rg] : swr;                                  \
      float avz = (u < 32) ? acc[1][rg] : swz;                                  \
      float avn = (u < 32) ? acc[2][rg] : swn;                                  \
      float rs = fsigm((float)GC[0][rg] + avr);                                 \
      float zs = fsigm((float)GC[1][rg] + avz);                                 \
      float ng = ftanh_((float)GC[2][rg] + rs * (avn + bn));                    \
      float hn = ng + zs * (h_old[rg] - ng);                                    \
      hn = ((dn4 >> (rg * 8)) & 0xff) ? 0.f : hn;                               \
      h_old[rg] = hn;                                                           \
      *(_Float16*)(hw + (wbase ^ (rg << 4))) = (_Float16)hn;                    \
    }                                                                           \
    asm volatile("s_waitcnt lgkmcnt(0)" ::: "memory");                          \
    __builtin_amdgcn_s_barrier();                                               \
  }

  for (int tl = 0; tl < tch; tl += 2) {
    STEP(tl, 0, gA, gB);
    STEP(tl + 1, 1, gB, gA);
  }
#undef STEP

  // carry h to next chunk
#pragma unroll
  for (int rg = 0; rg < 4; ++rg)
    ((float*)hcar)[(bt8 * 8 + rgrp * 4 + rg) * 256 + c] = h_old[rg];

  if (t0 + tch == TT) {
#pragma unroll
    for (int rg = 0; rg < 4; ++rg)
      out[2 * BB * AA + (bt8 * 8 + rgrp * 4 + rg) * 256 + c] = h_old[rg];
    // heads on h_final (read fp16 h from LDS buffer 0 — final parity after even tch)
    if (tid < 128) {
      int r2 = tid >> 4, a = (tid >> 1) & 7, hd = tid & 1;
      const float* W = hd ? Wsv : Wm;
      float acc2 = 0.f;
      for (int k = 0; k < 256; k += 8) {
        int ku = k >> 3;
        f16x8 vh = *(const f16x8*)(hro + ((ku * 256 + r2 * 16) ^ ((ku & 7) << 4)));
#pragma unroll
        for (int e = 0; e < 8; ++e)
          acc2 += (float)vh[e] * W[a * 256 + k + e];
      }
      int b = bt8 * 8 + r2;
      if (hd == 0) {
        out[b * AA + a] = tanhf(acc2 + bm[a]);
      } else {
        float v = acc2 + bsv[a];
        float sp = fmaxf(v, 0.f) + log1pf(expf(-fabsf(v)));
        out[BB * AA + b * AA + a] = fmaxf(sp, 1e-5f);
      }
    }
  }
}

extern "C" void kernel_launch(void* const* d_in, const int* in_sizes, int n_in,
                              void* d_out, int out_size, void* d_ws, size_t ws_size,
                              hipStream_t stream) {
  const float* x    = (const float*)d_in[0];
  const int*   dn   = (const int*)  d_in[1];
  const float* W1   = (const float*)d_in[2];
  const float* b1   = (const float*)d_in[3];
  const float* W_ih = (const float*)d_in[4];
  const float* W_hh = (const float*)d_in[5];
  const float* b_ih = (const float*)d_in[6];
  const float* b_hh = (const float*)d_in[7];
  const float* Wm   = (const float*)d_in[8];
  const float* bm   = (const float*)d_in[9];
  const float* Wsv  = (const float*)d_in[10];
  const float* bs   = (const float*)d_in[11];
  float* out = (float*)d_out;
  unsigned char* ws = (unsigned char*)d_ws;

  // largest chunk whose gi fits in ws; clamp to 256 (dnb/LDS sizing, even count)
  int tch = 256;
  while (tch > 1 && (size_t)OFF_GI + (size_t)tch * 16 * 24576 > ws_size) tch >>= 1;

  prepack<<<200, 256, 0, stream>>>(W1, W_ih, W_hh, ws);
  hipMemsetAsync(ws + OFF_H, 0, 262144, stream);
  for (int t0 = 0; t0 < TT; t0 += tch) {
    gru_gi<<<dim3(tch * 16), 256, 0, stream>>>(x, b1, b_ih, b_hh, ws, ws + OFF_GI, t0);
    gru_seq<<<32, 512, 0, stream>>>(dn, b_hh, Wm, bm, Wsv, bs, ws, ws + OFF_H,
                                    ws + OFF_GI, t0, tch, out);
  }
}

// Round 9
// 820.405 us; speedup vs baseline: 14.5781x; 1.0348x over previous
//
#include <hip/hip_runtime.h>
#include <math.h>

typedef __attribute__((ext_vector_type(8))) _Float16 f16x8;
typedef __attribute__((ext_vector_type(4))) _Float16 f16x4;
typedef __attribute__((ext_vector_type(2))) __fp16 h16x2;   // cvt_pkrtz result type
typedef __attribute__((ext_vector_type(4))) float f32x4;

#define TT 512
#define BB 256
#define HH 256
#define AA 8

// ws byte offsets
#define OFF_W1   0u           // 32 tiles  * 1024 B
#define OFF_WIH  32768u       // 384 tiles * 1024 B
#define OFF_WHH  425984u      // 384 tiles * 1024 B
#define OFF_H    819200u      // h_carry fp32 [256][256]
#define OFF_GI   1081344u     // gi fp16, per (t,bt16): 48*64*4*2 = 24576 B
#define GSTRIDE  393216       // gi bytes per timestep (16 bt16 tiles)

__device__ inline float fexp2(float x) { return __builtin_amdgcn_exp2f(x); }
__device__ inline float frcp(float x)  { return __builtin_amdgcn_rcpf(x); }
__device__ inline float fsigm(float x) { return frcp(1.f + fexp2(x * -1.4426950408889634f)); }
__device__ inline float ftanh_(float x){ return 1.f - 2.f * frcp(1.f + fexp2(x * 2.8853900817779268f)); }

// ---------------- phase 0: pack weights into fp16 MFMA B-fragments ----------
__global__ __launch_bounds__(256) void prepack(
    const float* __restrict__ W1, const float* __restrict__ Wih,
    const float* __restrict__ Whh, unsigned char* __restrict__ ws) {
  int gid = blockIdx.x * 256 + threadIdx.x;
  int wave = gid >> 6, l = gid & 63;
  const float* src; int K; int tix; size_t dst;
  if (wave < 32)       { src = W1;  K = 64;  tix = wave;       dst = OFF_W1; }
  else if (wave < 416) { src = Wih; K = 256; tix = wave - 32;  dst = OFF_WIH; }
  else                 { src = Whh; K = 256; tix = wave - 416; dst = OFF_WHH; }
  int ntJ = (K == 64) ? 16 : 48;
  int kt = tix / ntJ, jt = tix % ntJ;
  int j;
  if (K == 64) j = jt * 16 + (l & 15);
  else { int g = jt % 3, blk = jt / 3; j = g * 256 + blk * 16 + (l & 15); }
  int k = kt * 32 + (l >> 4) * 8;
  const float* p = src + (size_t)j * K + k;
  f16x8 frag;
#pragma unroll
  for (int e = 0; e < 8; ++e) frag[e] = (_Float16)p[e];
  *(f16x8*)(ws + dst + ((size_t)tix * 64 + l) * 16) = frag;
}

// ---------------- phase 1: gi = leakyrelu(x@W1^T+b1) @ W_ih^T + folded biases
// 2 timesteps per WG (halves W_ih L2 streaming).
__global__ __launch_bounds__(256) void gru_gi(
    const float* __restrict__ x, const float* __restrict__ b1,
    const float* __restrict__ b_ih, const float* __restrict__ b_hh,
    const unsigned char* __restrict__ wsro, unsigned char* __restrict__ giout,
    int t0) {
  __shared__ __align__(16) _Float16 sfh[2][16 * 256];
  int tid = threadIdx.x, w = tid >> 6, l = tid & 63;
  int tp = blockIdx.x >> 4, bt = blockIdx.x & 15;
  int row = l & 15, kg = l >> 4;

  const f16x8* pW1 = (const f16x8*)(wsro + OFF_W1);
#pragma unroll
  for (int tt = 0; tt < 2; ++tt) {
    int t = t0 + tp * 2 + tt;
    f32x4 sacc[4] = {{0.f,0.f,0.f,0.f},{0.f,0.f,0.f,0.f},{0.f,0.f,0.f,0.f},{0.f,0.f,0.f,0.f}};
    size_t xbase = ((size_t)t * BB + bt * 16 + row) * 64;
#pragma unroll
    for (int kt = 0; kt < 2; ++kt) {
      float4 p0 = *(const float4*)(x + xbase + kt * 32 + kg * 8);
      float4 p1 = *(const float4*)(x + xbase + kt * 32 + kg * 8 + 4);
      float xv[8] = {p0.x, p0.y, p0.z, p0.w, p1.x, p1.y, p1.z, p1.w};
      f16x8 xh;
#pragma unroll
      for (int e = 0; e < 8; ++e) xh[e] = (_Float16)xv[e];
#pragma unroll
      for (int jj = 0; jj < 4; ++jj) {
        f16x8 bw = pW1[(kt * 16 + w * 4 + jj) * 64 + l];
        sacc[jj] = __builtin_amdgcn_mfma_f32_16x16x32_f16(xh, bw, sacc[jj], 0, 0, 0);
      }
    }
#pragma unroll
    for (int jj = 0; jj < 4; ++jj) {
      int j = (w * 4 + jj) * 16 + row;
      float b1v = b1[j];
#pragma unroll
      for (int rg = 0; rg < 4; ++rg) {
        int rr = kg * 4 + rg;
        float v = sacc[jj][rg] + b1v;
        v = v >= 0.f ? v : 0.01f * v;
        int byt = (j * 2) ^ ((rr & 7) << 4);
        *(_Float16*)((char*)sfh[tt] + rr * 512 + byt) = (_Float16)v;
      }
    }
  }
  __syncthreads();

  f32x4 gacc[2][12];
#pragma unroll
  for (int tt = 0; tt < 2; ++tt)
#pragma unroll
    for (int jj = 0; jj < 12; ++jj) gacc[tt][jj] = (f32x4){0.f, 0.f, 0.f, 0.f};
  const f16x8* pWih = (const f16x8*)(wsro + OFF_WIH);
  for (int kt = 0; kt < 8; ++kt) {
    int rb = row * 512 + ((kt * 64 + kg * 16) ^ ((row & 7) << 4));
    f16x8 ah0 = *(const f16x8*)((const char*)sfh[0] + rb);
    f16x8 ah1 = *(const f16x8*)((const char*)sfh[1] + rb);
#pragma unroll
    for (int jj = 0; jj < 12; ++jj) {
      f16x8 bw = pWih[((size_t)(kt * 48 + w * 12 + jj)) * 64 + l];
      gacc[0][jj] = __builtin_amdgcn_mfma_f32_16x16x32_f16(ah0, bw, gacc[0][jj], 0, 0, 0);
      gacc[1][jj] = __builtin_amdgcn_mfma_f32_16x16x32_f16(ah1, bw, gacc[1][jj], 0, 0, 0);
    }
  }
  float biasv[12];
#pragma unroll
  for (int jj = 0; jj < 12; ++jj) {
    int jt = w * 12 + jj;
    int g = jt % 3, blk = jt / 3;
    int j = g * 256 + blk * 16 + row;
    biasv[jj] = b_ih[j] + (g < 2 ? b_hh[j] : 0.f);
  }
#pragma unroll
  for (int tt = 0; tt < 2; ++tt) {
    unsigned char* gbase =
        giout + (size_t)((tp * 2 + tt) * 16 + bt) * 24576 + (l >> 5) * 12288;
#pragma unroll
    for (int jj = 0; jj < 12; ++jj) {
      int jt = w * 12 + jj;
      f16x4 o;
#pragma unroll
      for (int rg = 0; rg < 4; ++rg) o[rg] = (_Float16)(gacc[tt][jj][rg] + biasv[jj]);
      *(f16x4*)(gbase + jt * 256 + (l & 31) * 8) = o;
    }
  }
}

// ---------------- phase 2: sequential GRU, 32 WGs (8 batch rows) x 512 thr ---
// W_hh register-resident; gi direct global->reg 1-step prefetch; K-major
// swizzled h LDS; broadcast-paired A-reads; packed-fp16 shfl compaction.
__global__ __launch_bounds__(512, 2) void gru_seq(
    const int* __restrict__ dones, const float* __restrict__ b_hh,
    const float* __restrict__ Wm, const float* __restrict__ bm,
    const float* __restrict__ Wsv, const float* __restrict__ bsv,
    const unsigned char* __restrict__ wsro, unsigned char* __restrict__ hcar,
    const unsigned char* __restrict__ gi, int t0, int tch,
    float* __restrict__ out) {
  __shared__ __align__(16) unsigned char hbuf[2][8192];  // K-major swizzled h
  __shared__ unsigned char dnb[2048];                    // packed dones bytes
  int tid = threadIdx.x, w = tid >> 6, u = tid & 63;
  int bt8 = blockIdx.x, bt16 = bt8 >> 1, half = bt8 & 1;
  int kg = u >> 4;                                         // A-frag k-group
  int col16 = u & 15, rgrp = (u >> 4) & 1, blk = u >> 5;   // update roles
  int c = (2 * w + blk) * 16 + col16;                      // owned h column

  // W_hh fragments: wave w owns jtn = 6w..6w+5 (blocks {2w,2w+1} x gates r,z,n)
  f16x8 whh[6][8];
  const f16x8* pWhh = (const f16x8*)(wsro + OFF_WHH);
#pragma unroll
  for (int jj = 0; jj < 6; ++jj)
#pragma unroll
    for (int kt = 0; kt < 8; ++kt)
      whh[jj][kt] = pWhh[(size_t)(kt * 48 + 6 * w + jj) * 64 + u];

  float bn = b_hh[512 + c];

  // loop-invariant LDS addresses; rows 8-15 alias rows 0-7 (broadcast pairs;
  // D rows 8-15 are never consumed)
  int ab0 = (kg * 256 + (u & 7) * 16) ^ (kg << 4);   // A-read base, even kt
  int ab1 = ab0 ^ 64;                                // odd kt
  int ku2 = c >> 3, e2 = c & 7;
  int wbase = (ku2 * 256 + rgrp * 64 + e2 * 2) ^ ((ku2 & 7) << 4);
  const char* hro = (const char*)hbuf;

  // zero rows 8-15 region (defensive; A-reads no longer touch it)
  {
    int buf = tid >> 8, r = tid & 255;
    f16x8 z;
#pragma unroll
    for (int e = 0; e < 8; ++e) z[e] = (_Float16)0.f;
    *(f16x8*)((char*)hbuf + buf * 8192 + (r >> 3) * 256 + 128 + (r & 7) * 16) = z;
  }

  // h_old init + hbuf[0] rows 0..7
  float h_old[4];
#pragma unroll
  for (int rg = 0; rg < 4; ++rg) {
    float hv = ((const float*)hcar)[(bt8 * 8 + rgrp * 4 + rg) * 256 + c];
    h_old[rg] = hv;
    *(_Float16*)((char*)hbuf + (wbase ^ (rg << 4))) = (_Float16)hv;
  }

  // preload ALL (shifted) dones for this chunk as bytes
#pragma unroll
  for (int ii = 0; ii < 4; ++ii) {
    int ix = ii * 512 + tid;
    if (ix < tch * 8) {
      int ti = t0 + (ix >> 3) + 1;
      dnb[ix] = (ti < TT) ? (unsigned char)(dones[ti * BB + bt8 * 8 + (ix & 7)] != 0) : (unsigned char)0;
    }
  }

  // gi per-thread pointer (layout matches producer exactly)
  const unsigned char* gpt = gi + (size_t)bt16 * 24576 + half * 12288 +
                             (2 * w + blk) * 768 + (u & 31) * 8;
  f16x4 gA[3], gB[3];
#pragma unroll
  for (int g = 0; g < 3; ++g) gA[g] = *(const f16x4*)(gpt + g * 256);

  asm volatile("s_waitcnt lgkmcnt(0)" ::: "memory");
  __builtin_amdgcn_s_barrier();

#define STEP(TL, P, GC, GN)                                                     \
  {                                                                             \
    int tn = (TL) + 1 < tch ? (TL) + 1 : tch - 1;                               \
    const unsigned char* gpn = gpt + (size_t)tn * GSTRIDE;                      \
    GN[0] = *(const f16x4*)(gpn);                                               \
    GN[1] = *(const f16x4*)(gpn + 256);                                         \
    GN[2] = *(const f16x4*)(gpn + 512);                                         \
    f32x4 acc[6];                                                               \
    _Pragma("unroll") for (int jj = 0; jj < 6; ++jj)                            \
        acc[jj] = (f32x4){0.f, 0.f, 0.f, 0.f};                                  \
    _Pragma("unroll") for (int kt = 0; kt < 8; ++kt) {                          \
      f16x8 ah = *(const f16x8*)(hro + (P) * 8192 + kt * 1024 +                 \
                                 ((kt & 1) ? ab1 : ab0));                       \
      _Pragma("unroll") for (int jj = 0; jj < 6; ++jj)                          \
        acc[jj] = __builtin_amdgcn_mfma_f32_16x16x32_f16(ah, whh[jj][kt],       \
                                                         acc[jj], 0, 0, 0);     \
    }                                                                           \
    int s01[3], s23[3];                                                         \
    _Pragma("unroll") for (int g = 0; g < 3; ++g) {                             \
      h16x2 p01 = __builtin_amdgcn_cvt_pkrtz(acc[3 + g][0], acc[3 + g][1]);     \
      h16x2 p23 = __builtin_amdgcn_cvt_pkrtz(acc[3 + g][2], acc[3 + g][3]);     \
      s01[g] = __shfl_xor(__builtin_bit_cast(int, p01), 32);                    \
      s23[g] = __shfl_xor(__builtin_bit_cast(int, p23), 32);                    \
    }                                                                           \
    int dn4 = *(const int*)(dnb + (TL) * 8 + rgrp * 4);                         \
    char* hw = (char*)hbuf + ((P) ^ 1) * 8192;                                  \
    _Pragma("unroll") for (int rg = 0; rg < 4; ++rg) {                          \
      float avr = (u < 32) ? acc[0][rg]                                         \
          : (float)(((rg < 2) ? __builtin_bit_cast(h16x2, s01[0])               \
                              : __builtin_bit_cast(h16x2, s23[0]))[rg & 1]);    \
      float avz = (u < 32) ? acc[1][rg]                                         \
          : (float)(((rg < 2) ? __builtin_bit_cast(h16x2, s01[1])               \
                              : __builtin_bit_cast(h16x2, s23[1]))[rg & 1]);    \
      float avn = (u < 32) ? acc[2][rg]                                         \
          : (float)(((rg < 2) ? __builtin_bit_cast(h16x2, s01[2])               \
                              : __builtin_bit_cast(h16x2, s23[2]))[rg & 1]);    \
      float rs = fsigm((float)GC[0][rg] + avr);                                 \
      float zs = fsigm((float)GC[1][rg] + avz);                                 \
      float ng = ftanh_((float)GC[2][rg] + rs * (avn + bn));                    \
      float hn = ng + zs * (h_old[rg] - ng);                                    \
      hn = ((dn4 >> (rg * 8)) & 0xff) ? 0.f : hn;                               \
      h_old[rg] = hn;                                                           \
      *(_Float16*)(hw + (wbase ^ (rg << 4))) = (_Float16)hn;                    \
    }                                                                           \
    asm volatile("s_waitcnt lgkmcnt(0)" ::: "memory");                          \
    __builtin_amdgcn_s_barrier();                                               \
  }

  for (int tl = 0; tl < tch; tl += 2) {
    STEP(tl, 0, gA, gB);
    STEP(tl + 1, 1, gB, gA);
  }
#undef STEP

  // carry h to next chunk
#pragma unroll
  for (int rg = 0; rg < 4; ++rg)
    ((float*)hcar)[(bt8 * 8 + rgrp * 4 + rg) * 256 + c] = h_old[rg];

  if (t0 + tch == TT) {
#pragma unroll
    for (int rg = 0; rg < 4; ++rg)
      out[2 * BB * AA + (bt8 * 8 + rgrp * 4 + rg) * 256 + c] = h_old[rg];
    // heads on h_final (read fp16 h from LDS buffer 0 — final parity after even tch)
    if (tid < 128) {
      int r2 = tid >> 4, a = (tid >> 1) & 7, hd = tid & 1;
      const float* W = hd ? Wsv : Wm;
      float acc2 = 0.f;
      for (int k = 0; k < 256; k += 8) {
        int ku = k >> 3;
        f16x8 vh = *(const f16x8*)(hro + ((ku * 256 + r2 * 16) ^ ((ku & 7) << 4)));
#pragma unroll
        for (int e = 0; e < 8; ++e)
          acc2 += (float)vh[e] * W[a * 256 + k + e];
      }
      int b = bt8 * 8 + r2;
      if (hd == 0) {
        out[b * AA + a] = tanhf(acc2 + bm[a]);
      } else {
        float v = acc2 + bsv[a];
        float sp = fmaxf(v, 0.f) + log1pf(expf(-fabsf(v)));
        out[BB * AA + b * AA + a] = fmaxf(sp, 1e-5f);
      }
    }
  }
}

extern "C" void kernel_launch(void* const* d_in, const int* in_sizes, int n_in,
                              void* d_out, int out_size, void* d_ws, size_t ws_size,
                              hipStream_t stream) {
  const float* x    = (const float*)d_in[0];
  const int*   dn   = (const int*)  d_in[1];
  const float* W1   = (const float*)d_in[2];
  const float* b1   = (const float*)d_in[3];
  const float* W_ih = (const float*)d_in[4];
  const float* W_hh = (const float*)d_in[5];
  const float* b_ih = (const float*)d_in[6];
  const float* b_hh = (const float*)d_in[7];
  const float* Wm   = (const float*)d_in[8];
  const float* bm   = (const float*)d_in[9];
  const float* Wsv  = (const float*)d_in[10];
  const float* bs   = (const float*)d_in[11];
  float* out = (float*)d_out;
  unsigned char* ws = (unsigned char*)d_ws;

  // largest chunk whose gi fits in ws; clamp to 256 (dnb/LDS sizing, even count)
  int tch = 256;
  while (tch > 1 && (size_t)OFF_GI + (size_t)tch * 16 * 24576 > ws_size) tch >>= 1;

  prepack<<<200, 256, 0, stream>>>(W1, W_ih, W_hh, ws);
  (void)hipMemsetAsync(ws + OFF_H, 0, 262144, stream);
  for (int t0 = 0; t0 < TT; t0 += tch) {
    gru_gi<<<dim3((tch / 2) * 16), 256, 0, stream>>>(x, b1, b_ih, b_hh, ws, ws + OFF_GI, t0);
    gru_seq<<<32, 512, 0, stream>>>(dn, b_hh, Wm, bm, Wsv, bs, ws, ws + OFF_H,
                                    ws + OFF_GI, t0, tch, out);
  }
}

// Round 10
// 791.107 us; speedup vs baseline: 15.1179x; 1.0370x over previous
//
#include <hip/hip_runtime.h>
#include <math.h>

typedef __attribute__((ext_vector_type(8))) _Float16 f16x8;
typedef __attribute__((ext_vector_type(4))) _Float16 f16x4;
typedef __attribute__((ext_vector_type(4))) float f32x4;

#define TT 512
#define BB 256
#define HH 256
#define AA 8

// ws byte offsets
#define OFF_W1   0u           // 32 tiles  * 1024 B
#define OFF_WIH  32768u       // 384 tiles * 1024 B
#define OFF_WHH  425984u      // 384 tiles * 1024 B
#define OFF_H    819200u      // h_carry fp32 [256][256]
#define OFF_GI   1081344u     // gi fp16, per (t,bt16): 48*64*4*2 = 24576 B
#define GSTRIDE  393216       // gi bytes per timestep (16 bt16 tiles)

__device__ inline float fexp2(float x) { return __builtin_amdgcn_exp2f(x); }
__device__ inline float frcp(float x)  { return __builtin_amdgcn_rcpf(x); }
__device__ inline float fsigm(float x) { return frcp(1.f + fexp2(x * -1.4426950408889634f)); }
__device__ inline float ftanh_(float x){ return 1.f - 2.f * frcp(1.f + fexp2(x * 2.8853900817779268f)); }

// ---------------- phase 0: pack weights into fp16 MFMA B-fragments ----------
__global__ __launch_bounds__(256) void prepack(
    const float* __restrict__ W1, const float* __restrict__ Wih,
    const float* __restrict__ Whh, unsigned char* __restrict__ ws) {
  int gid = blockIdx.x * 256 + threadIdx.x;
  int wave = gid >> 6, l = gid & 63;
  const float* src; int K; int tix; size_t dst;
  if (wave < 32)       { src = W1;  K = 64;  tix = wave;       dst = OFF_W1; }
  else if (wave < 416) { src = Wih; K = 256; tix = wave - 32;  dst = OFF_WIH; }
  else                 { src = Whh; K = 256; tix = wave - 416; dst = OFF_WHH; }
  int ntJ = (K == 64) ? 16 : 48;
  int kt = tix / ntJ, jt = tix % ntJ;
  int j;
  if (K == 64) j = jt * 16 + (l & 15);
  else { int g = jt % 3, blk = jt / 3; j = g * 256 + blk * 16 + (l & 15); }
  int k = kt * 32 + (l >> 4) * 8;
  const float* p = src + (size_t)j * K + k;
  f16x8 frag;
#pragma unroll
  for (int e = 0; e < 8; ++e) frag[e] = (_Float16)p[e];
  *(f16x8*)(ws + dst + ((size_t)tix * 64 + l) * 16) = frag;
}

// ---------------- phase 1: gi = leakyrelu(x@W1^T+b1) @ W_ih^T + folded biases
// 2 timesteps per WG (halves W_ih L2 streaming).
__global__ __launch_bounds__(256) void gru_gi(
    const float* __restrict__ x, const float* __restrict__ b1,
    const float* __restrict__ b_ih, const float* __restrict__ b_hh,
    const unsigned char* __restrict__ wsro, unsigned char* __restrict__ giout,
    int t0) {
  __shared__ __align__(16) _Float16 sfh[2][16 * 256];
  int tid = threadIdx.x, w = tid >> 6, l = tid & 63;
  int tp = blockIdx.x >> 4, bt = blockIdx.x & 15;
  int row = l & 15, kg = l >> 4;

  const f16x8* pW1 = (const f16x8*)(wsro + OFF_W1);
#pragma unroll
  for (int tt = 0; tt < 2; ++tt) {
    int t = t0 + tp * 2 + tt;
    f32x4 sacc[4] = {{0.f,0.f,0.f,0.f},{0.f,0.f,0.f,0.f},{0.f,0.f,0.f,0.f},{0.f,0.f,0.f,0.f}};
    size_t xbase = ((size_t)t * BB + bt * 16 + row) * 64;
#pragma unroll
    for (int kt = 0; kt < 2; ++kt) {
      float4 p0 = *(const float4*)(x + xbase + kt * 32 + kg * 8);
      float4 p1 = *(const float4*)(x + xbase + kt * 32 + kg * 8 + 4);
      float xv[8] = {p0.x, p0.y, p0.z, p0.w, p1.x, p1.y, p1.z, p1.w};
      f16x8 xh;
#pragma unroll
      for (int e = 0; e < 8; ++e) xh[e] = (_Float16)xv[e];
#pragma unroll
      for (int jj = 0; jj < 4; ++jj) {
        f16x8 bw = pW1[(kt * 16 + w * 4 + jj) * 64 + l];
        sacc[jj] = __builtin_amdgcn_mfma_f32_16x16x32_f16(xh, bw, sacc[jj], 0, 0, 0);
      }
    }
#pragma unroll
    for (int jj = 0; jj < 4; ++jj) {
      int j = (w * 4 + jj) * 16 + row;
      float b1v = b1[j];
#pragma unroll
      for (int rg = 0; rg < 4; ++rg) {
        int rr = kg * 4 + rg;
        float v = sacc[jj][rg] + b1v;
        v = v >= 0.f ? v : 0.01f * v;
        int byt = (j * 2) ^ ((rr & 7) << 4);
        *(_Float16*)((char*)sfh[tt] + rr * 512 + byt) = (_Float16)v;
      }
    }
  }
  __syncthreads();

  f32x4 gacc[2][12];
#pragma unroll
  for (int tt = 0; tt < 2; ++tt)
#pragma unroll
    for (int jj = 0; jj < 12; ++jj) gacc[tt][jj] = (f32x4){0.f, 0.f, 0.f, 0.f};
  const f16x8* pWih = (const f16x8*)(wsro + OFF_WIH);
  for (int kt = 0; kt < 8; ++kt) {
    int rb = row * 512 + ((kt * 64 + kg * 16) ^ ((row & 7) << 4));
    f16x8 ah0 = *(const f16x8*)((const char*)sfh[0] + rb);
    f16x8 ah1 = *(const f16x8*)((const char*)sfh[1] + rb);
#pragma unroll
    for (int jj = 0; jj < 12; ++jj) {
      f16x8 bw = pWih[((size_t)(kt * 48 + w * 12 + jj)) * 64 + l];
      gacc[0][jj] = __builtin_amdgcn_mfma_f32_16x16x32_f16(ah0, bw, gacc[0][jj], 0, 0, 0);
      gacc[1][jj] = __builtin_amdgcn_mfma_f32_16x16x32_f16(ah1, bw, gacc[1][jj], 0, 0, 0);
    }
  }
  float biasv[12];
#pragma unroll
  for (int jj = 0; jj < 12; ++jj) {
    int jt = w * 12 + jj;
    int g = jt % 3, blk = jt / 3;
    int j = g * 256 + blk * 16 + row;
    biasv[jj] = b_ih[j] + (g < 2 ? b_hh[j] : 0.f);
  }
#pragma unroll
  for (int tt = 0; tt < 2; ++tt) {
    unsigned char* gbase =
        giout + (size_t)((tp * 2 + tt) * 16 + bt) * 24576 + (l >> 5) * 12288;
#pragma unroll
    for (int jj = 0; jj < 12; ++jj) {
      int jt = w * 12 + jj;
      f16x4 o;
#pragma unroll
      for (int rg = 0; rg < 4; ++rg) o[rg] = (_Float16)(gacc[tt][jj][rg] + biasv[jj]);
      *(f16x4*)(gbase + jt * 256 + (l & 31) * 8) = o;
    }
  }
}

// ---------------- phase 2: sequential GRU, 32 WGs (8 batch rows) x 512 thr ---
// W_hh register-resident; gi direct global->reg 1-step prefetch; K-major
// swizzled h LDS; broadcast-paired A-reads. Key insight: with A rows 8-15
// aliasing rows 0-7, D rows 8-15 (lanes 32-63) are bit-exact copies of rows
// 0-7 for ALL acc tiles -> lanes >=32 already hold block-1 values for their
// update rows. No compaction shuffle needed at all.
__global__ __launch_bounds__(512, 2) void gru_seq(
    const int* __restrict__ dones, const float* __restrict__ b_hh,
    const float* __restrict__ Wm, const float* __restrict__ bm,
    const float* __restrict__ Wsv, const float* __restrict__ bsv,
    const unsigned char* __restrict__ wsro, unsigned char* __restrict__ hcar,
    const unsigned char* __restrict__ gi, int t0, int tch,
    float* __restrict__ out) {
  __shared__ __align__(16) unsigned char hbuf[2][8192];  // K-major swizzled h
  __shared__ unsigned char dnb[2048];                    // packed dones bytes
  int tid = threadIdx.x, w = tid >> 6, u = tid & 63;
  int bt8 = blockIdx.x, bt16 = bt8 >> 1, half = bt8 & 1;
  int kg = u >> 4;                                         // A-frag k-group
  int col16 = u & 15, rgrp = (u >> 4) & 1, blk = u >> 5;   // update roles
  int c = (2 * w + blk) * 16 + col16;                      // owned h column

  // W_hh fragments: wave w owns jtn = 6w..6w+5 (blocks {2w,2w+1} x gates r,z,n)
  f16x8 whh[6][8];
  const f16x8* pWhh = (const f16x8*)(wsro + OFF_WHH);
#pragma unroll
  for (int jj = 0; jj < 6; ++jj)
#pragma unroll
    for (int kt = 0; kt < 8; ++kt)
      whh[jj][kt] = pWhh[(size_t)(kt * 48 + 6 * w + jj) * 64 + u];

  float bn = b_hh[512 + c];

  // loop-invariant LDS addresses; rows 8-15 alias rows 0-7 (broadcast pairs;
  // D rows 8-15 = exact copies of rows 0-7, consumed in-lane by the update)
  int ab0 = (kg * 256 + (u & 7) * 16) ^ (kg << 4);   // A-read base, even kt
  int ab1 = ab0 ^ 64;                                // odd kt
  int ku2 = c >> 3, e2 = c & 7;
  int wbase = (ku2 * 256 + rgrp * 64 + e2 * 2) ^ ((ku2 & 7) << 4);
  const char* hro = (const char*)hbuf;

  // zero rows 8-15 region (defensive; A-reads no longer touch it)
  {
    int buf = tid >> 8, r = tid & 255;
    f16x8 z;
#pragma unroll
    for (int e = 0; e < 8; ++e) z[e] = (_Float16)0.f;
    *(f16x8*)((char*)hbuf + buf * 8192 + (r >> 3) * 256 + 128 + (r & 7) * 16) = z;
  }

  // h_old init + hbuf[0] rows 0..7
  float h_old[4];
#pragma unroll
  for (int rg = 0; rg < 4; ++rg) {
    float hv = ((const float*)hcar)[(bt8 * 8 + rgrp * 4 + rg) * 256 + c];
    h_old[rg] = hv;
    *(_Float16*)((char*)hbuf + (wbase ^ (rg << 4))) = (_Float16)hv;
  }

  // preload ALL (shifted) dones for this chunk as bytes
#pragma unroll
  for (int ii = 0; ii < 4; ++ii) {
    int ix = ii * 512 + tid;
    if (ix < tch * 8) {
      int ti = t0 + (ix >> 3) + 1;
      dnb[ix] = (ti < TT) ? (unsigned char)(dones[ti * BB + bt8 * 8 + (ix & 7)] != 0) : (unsigned char)0;
    }
  }

  // gi per-thread pointer (layout matches producer exactly)
  const unsigned char* gpt = gi + (size_t)bt16 * 24576 + half * 12288 +
                             (2 * w + blk) * 768 + (u & 31) * 8;
  f16x4 gA[3], gB[3];
#pragma unroll
  for (int g = 0; g < 3; ++g) gA[g] = *(const f16x4*)(gpt + g * 256);

  asm volatile("s_waitcnt lgkmcnt(0)" ::: "memory");
  __builtin_amdgcn_s_barrier();

#define STEP(TL, P, GC, GN)                                                     \
  {                                                                             \
    int tn = (TL) + 1 < tch ? (TL) + 1 : tch - 1;                               \
    const unsigned char* gpn = gpt + (size_t)tn * GSTRIDE;                      \
    GN[0] = *(const f16x4*)(gpn);                                               \
    GN[1] = *(const f16x4*)(gpn + 256);                                         \
    GN[2] = *(const f16x4*)(gpn + 512);                                         \
    f32x4 acc[6];                                                               \
    _Pragma("unroll") for (int jj = 0; jj < 6; ++jj)                            \
        acc[jj] = (f32x4){0.f, 0.f, 0.f, 0.f};                                  \
    _Pragma("unroll") for (int kt = 0; kt < 8; ++kt) {                          \
      f16x8 ah = *(const f16x8*)(hro + (P) * 8192 + kt * 1024 +                 \
                                 ((kt & 1) ? ab1 : ab0));                       \
      _Pragma("unroll") for (int jj = 0; jj < 6; ++jj)                          \
        acc[jj] = __builtin_amdgcn_mfma_f32_16x16x32_f16(ah, whh[jj][kt],       \
                                                         acc[jj], 0, 0, 0);     \
    }                                                                           \
    int dn4 = *(const int*)(dnb + (TL) * 8 + rgrp * 4);                         \
    char* hw = (char*)hbuf + ((P) ^ 1) * 8192;                                  \
    _Pragma("unroll") for (int rg = 0; rg < 4; ++rg) {                          \
      float avr = blk ? acc[3][rg] : acc[0][rg];                                \
      float avz = blk ? acc[4][rg] : acc[1][rg];                                \
      float avn = blk ? acc[5][rg] : acc[2][rg];                                \
      float rs = fsigm((float)GC[0][rg] + avr);                                 \
      float zs = fsigm((float)GC[1][rg] + avz);                                 \
      float ng = ftanh_((float)GC[2][rg] + rs * (avn + bn));                    \
      float hn = ng + zs * (h_old[rg] - ng);                                    \
      hn = ((dn4 >> (rg * 8)) & 0xff) ? 0.f : hn;                               \
      h_old[rg] = hn;                                                           \
      *(_Float16*)(hw + (wbase ^ (rg << 4))) = (_Float16)hn;                    \
    }                                                                           \
    asm volatile("s_waitcnt lgkmcnt(0)" ::: "memory");                          \
    __builtin_amdgcn_s_barrier();                                               \
  }

  for (int tl = 0; tl < tch; tl += 2) {
    STEP(tl, 0, gA, gB);
    STEP(tl + 1, 1, gB, gA);
  }
#undef STEP

  // carry h to next chunk
#pragma unroll
  for (int rg = 0; rg < 4; ++rg)
    ((float*)hcar)[(bt8 * 8 + rgrp * 4 + rg) * 256 + c] = h_old[rg];

  if (t0 + tch == TT) {
#pragma unroll
    for (int rg = 0; rg < 4; ++rg)
      out[2 * BB * AA + (bt8 * 8 + rgrp * 4 + rg) * 256 + c] = h_old[rg];
    // heads on h_final (read fp16 h from LDS buffer 0 — final parity after even tch)
    if (tid < 128) {
      int r2 = tid >> 4, a = (tid >> 1) & 7, hd = tid & 1;
      const float* W = hd ? Wsv : Wm;
      float acc2 = 0.f;
      for (int k = 0; k < 256; k += 8) {
        int ku = k >> 3;
        f16x8 vh = *(const f16x8*)(hro + ((ku * 256 + r2 * 16) ^ ((ku & 7) << 4)));
#pragma unroll
        for (int e = 0; e < 8; ++e)
          acc2 += (float)vh[e] * W[a * 256 + k + e];
      }
      int b = bt8 * 8 + r2;
      if (hd == 0) {
        out[b * AA + a] = tanhf(acc2 + bm[a]);
      } else {
        float v = acc2 + bsv[a];
        float sp = fmaxf(v, 0.f) + log1pf(expf(-fabsf(v)));
        out[BB * AA + b * AA + a] = fmaxf(sp, 1e-5f);
      }
    }
  }
}

extern "C" void kernel_launch(void* const* d_in, const int* in_sizes, int n_in,
                              void* d_out, int out_size, void* d_ws, size_t ws_size,
                              hipStream_t stream) {
  const float* x    = (const float*)d_in[0];
  const int*   dn   = (const int*)  d_in[1];
  const float* W1   = (const float*)d_in[2];
  const float* b1   = (const float*)d_in[3];
  const float* W_ih = (const float*)d_in[4];
  const float* W_hh = (const float*)d_in[5];
  const float* b_ih = (const float*)d_in[6];
  const float* b_hh = (const float*)d_in[7];
  const float* Wm   = (const float*)d_in[8];
  const float* bm   = (const float*)d_in[9];
  const float* Wsv  = (const float*)d_in[10];
  const float* bs   = (const float*)d_in[11];
  float* out = (float*)d_out;
  unsigned char* ws = (unsigned char*)d_ws;

  // largest chunk whose gi fits in ws; clamp to 256 (dnb/LDS sizing, even count)
  int tch = 256;
  while (tch > 1 && (size_t)OFF_GI + (size_t)tch * 16 * 24576 > ws_size) tch >>= 1;

  prepack<<<200, 256, 0, stream>>>(W1, W_ih, W_hh, ws);
  (void)hipMemsetAsync(ws + OFF_H, 0, 262144, stream);
  for (int t0 = 0; t0 < TT; t0 += tch) {
    gru_gi<<<dim3((tch / 2) * 16), 256, 0, stream>>>(x, b1, b_ih, b_hh, ws, ws + OFF_GI, t0);
    gru_seq<<<32, 512, 0, stream>>>(dn, b_hh, Wm, bm, Wsv, bs, ws, ws + OFF_H,
                                    ws + OFF_GI, t0, tch, out);
  }
}